// Round 5
// baseline (469.515 us; speedup 1.0000x reference)
//
#include <hip/hip_runtime.h>
#include <hip/hip_bf16.h>
#include <math.h>

#define NN 10000
#define J48 10048          // epart padded i-extent (157*64)
#define DJ 10112           // dpart padded j-extent (79*128)
#define DSPLITS 16
#define DCPS 10            // i-chunks (of 64 rows) per d-split; 157 total
#define DCHUNKS 157
#define ESPLITS 8
#define ECPS 10            // j-chunks (of 128) per e-split; 79 total
#define ECHUNKS 79

typedef __bf16 bf16;
typedef bf16 bf16x8 __attribute__((ext_vector_type(8)));
typedef float f32x4 __attribute__((ext_vector_type(4)));

__device__ __forceinline__ float wave_sum64(float v) {
#pragma unroll
  for (int m = 32; m >= 1; m >>= 1) v += __shfl_xor(v, m, 64);
  return v;
}

// ---------------------------------------------------------------- prep
__global__ void prep_kernel(const float* __restrict__ w1, const float* __restrict__ w2,
                            const float* __restrict__ wq1, const float* __restrict__ wk1,
                            const float* __restrict__ wq2, const float* __restrict__ wk2,
                            const float* __restrict__ wvw,
                            const float* __restrict__ bq1, const float* __restrict__ bk1,
                            const float* __restrict__ bq2, const float* __restrict__ bk2,
                            const float* __restrict__ bvv,
                            const float* __restrict__ lq1, const float* __restrict__ lk1,
                            const float* __restrict__ lq2, const float* __restrict__ lk2,
                            const float* __restrict__ freq_deltas, const float* __restrict__ freq_bias,
                            bf16* __restrict__ w1T, bf16* __restrict__ w2T, bf16* __restrict__ qkvT,
                            float* __restrict__ bqkv, float* __restrict__ freqs, float* __restrict__ lamb) {
  int tid = blockIdx.x * blockDim.x + threadIdx.x;
  int nthr = gridDim.x * blockDim.x;
  for (int i = tid; i < 512 * 128; i += nthr) {
    int o = i >> 9, k = i & 511;
    w1T[i] = (bf16)w1[k * 128 + o];
  }
  for (int i = tid; i < 64 * 128; i += nthr) {
    int o = i >> 7, k = i & 127;
    w2T[i] = (bf16)w2[k * 64 + o];
  }
  for (int i = tid; i < 320 * 64; i += nthr) {
    int r = i >> 6, k = i & 63;
    const float* W = (r < 64) ? wq1 : (r < 128) ? wk1 : (r < 192) ? wq2 : (r < 256) ? wk2 : wvw;
    qkvT[i] = (bf16)W[k * 64 + (r & 63)];
  }
  for (int i = tid; i < 320; i += nthr) {
    const float* B = (i < 64) ? bq1 : (i < 128) ? bk1 : (i < 192) ? bq2 : (i < 256) ? bk2 : bvv;
    bqkv[i] = B[i & 63];
  }
  if (blockIdx.x == 0) {
    if (threadIdx.x == 0) {
      float acc = freq_bias[0];
      for (int f = 0; f < 16; f++) {
        acc += log1pf(expf(freq_deltas[f])) + 0.25f;
        freqs[f] = 50.0f * tanhf(acc * (1.0f / 50.0f));
      }
    }
    if (threadIdx.x >= 64 && threadIdx.x < 128) {
      int l = threadIdx.x - 64;
      float s1 = wave_sum64(lq1[l] * lk1[l]);
      float s2 = wave_sum64(lq2[l] * lk2[l]);
      if (l == 0) lamb[0] = expf(s1) - expf(s2) + 0.2f;
    }
  }
}

// ---------------------------------------------------------------- new_e
__global__ void newe_kernel(const float* __restrict__ e, const float* __restrict__ rw,
                            const float* __restrict__ rb, const float* __restrict__ aw,
                            const float* __restrict__ freqs, float* __restrict__ newe) {
  int n = blockIdx.x * blockDim.x + threadIdx.x;
  if (n >= NN) return;
  float fr[16];
#pragma unroll
  for (int f = 0; f < 16; f++) fr[f] = freqs[f];
  float ev = e[n], p = 1.0f, acc = 0.0f;
  for (int k = 0; k < 10; k++) {
    p *= ev;
    float s = rb[k] + rw[k * 33];
#pragma unroll
    for (int f = 0; f < 16; f++) {
      float ph = p * fr[f];
      s += 0.25f * (__sinf(ph) * rw[k * 33 + 1 + f] + __cosf(ph) * rw[k * 33 + 17 + f]);
    }
    acc += s * aw[k];
  }
  newe[n] = acc;
}

// ---------------------------------------------------------------- G1
__global__ __launch_bounds__(256) void g1_kernel(const float* __restrict__ x, const bf16* __restrict__ w1T,
                                                 const float* __restrict__ b1, bf16* __restrict__ t1b) {
  __shared__ bf16 la[64][40];
  __shared__ bf16 lb[128][40];
  const int bm = blockIdx.x * 64;
  const int lane = threadIdx.x & 63, wvid = threadIdx.x >> 6;
  const int am = threadIdx.x >> 2, aseg = (threadIdx.x & 3) * 8;
  const int arow = bm + am;
  f32x4 acc[8] = {};
  float4 aLo, aHi;
  uint4 bChunk[2];
  auto fetchAll = [&](int k0) {
    if (arow < NN) {
      const float4* p = (const float4*)(x + (size_t)arow * 512 + k0 + aseg);
      aLo = p[0]; aHi = p[1];
    } else {
      aLo = make_float4(0.f, 0.f, 0.f, 0.f); aHi = aLo;
    }
#pragma unroll
    for (int r = 0; r < 2; r++) {
      int slot = threadIdx.x * 2 + r;
      int n = slot >> 2, seg = (slot & 3) * 8;
      bChunk[r] = *(const uint4*)(w1T + n * 512 + k0 + seg);
    }
  };
  auto store = [&]() {
    union { uint4 v; bf16 b[8]; } pk;
    float av[8] = {aLo.x, aLo.y, aLo.z, aLo.w, aHi.x, aHi.y, aHi.z, aHi.w};
#pragma unroll
    for (int t = 0; t < 8; t++) pk.b[t] = (bf16)av[t];
    *(uint4*)&la[am][aseg] = pk.v;
#pragma unroll
    for (int r = 0; r < 2; r++) {
      int slot = threadIdx.x * 2 + r;
      int n = slot >> 2, seg = (slot & 3) * 8;
      *(uint4*)&lb[n][seg] = bChunk[r];
    }
  };
  fetchAll(0);
  for (int k0 = 0; k0 < 512; k0 += 32) {
    store();
    if (k0 + 32 < 512) fetchAll(k0 + 32);
    __syncthreads();
    bf16x8 af = *(const bf16x8*)&la[wvid * 16 + (lane & 15)][(lane >> 4) * 8];
#pragma unroll
    for (int s = 0; s < 8; s++) {
      bf16x8 bfr = *(const bf16x8*)&lb[s * 16 + (lane & 15)][(lane >> 4) * 8];
      acc[s] = __builtin_amdgcn_mfma_f32_16x16x32_bf16(af, bfr, acc[s], 0, 0, 0);
    }
    __syncthreads();
  }
#pragma unroll
  for (int s = 0; s < 8; s++) {
    int col = s * 16 + (lane & 15);
    float bvv = b1[col];
#pragma unroll
    for (int r = 0; r < 4; r++) {
      int row = bm + wvid * 16 + (lane >> 4) * 4 + r;
      if (row < NN) {
        float v = acc[s][r] + bvv;
        t1b[(size_t)row * 128 + col] = (bf16)(v > 0.f ? v : 0.f);
      }
    }
  }
}

// ---------------------------------------------------------------- G2 (+ fused mha-LN epilogue)
__global__ __launch_bounds__(256) void g2_kernel(const bf16* __restrict__ t1b, const bf16* __restrict__ w2T,
                                                 const float* __restrict__ b2, const float* __restrict__ lng,
                                                 const float* __restrict__ lnb, float* __restrict__ h,
                                                 bf16* __restrict__ hT, bf16* __restrict__ mh) {
  __shared__ bf16 la[64][72];
  __shared__ bf16 lb[64][72];
  const int bm = blockIdx.x * 64;
  const int lane = threadIdx.x & 63, wvid = threadIdx.x >> 6;
  f32x4 acc[4] = {};
  for (int k0 = 0; k0 < 128; k0 += 64) {
#pragma unroll
    for (int r = 0; r < 2; r++) {
      int slot = threadIdx.x * 2 + r;
      int m = slot >> 3, seg = (slot & 7) * 8;
      int row = bm + m;
      uint4 val = make_uint4(0u, 0u, 0u, 0u);
      if (row < NN) val = *(const uint4*)(t1b + (size_t)row * 128 + k0 + seg);
      *(uint4*)&la[m][seg] = val;
      *(uint4*)&lb[m][seg] = *(const uint4*)(w2T + m * 128 + k0 + seg);
    }
    __syncthreads();
#pragma unroll
    for (int ks = 0; ks < 2; ks++) {
      bf16x8 af = *(const bf16x8*)&la[wvid * 16 + (lane & 15)][ks * 32 + (lane >> 4) * 8];
#pragma unroll
      for (int s = 0; s < 4; s++) {
        bf16x8 bfr = *(const bf16x8*)&lb[s * 16 + (lane & 15)][ks * 32 + (lane >> 4) * 8];
        acc[s] = __builtin_amdgcn_mfma_f32_16x16x32_bf16(af, bfr, acc[s], 0, 0, 0);
      }
    }
    __syncthreads();
  }
  float bv4[4], g4[4], lb4[4];
#pragma unroll
  for (int s = 0; s < 4; s++) {
    int col = s * 16 + (lane & 15);
    bv4[s] = b2[col]; g4[s] = lng[col]; lb4[s] = lnb[col];
  }
#pragma unroll
  for (int r = 0; r < 4; r++) {
    float vals[4], psum = 0.f;
#pragma unroll
    for (int s = 0; s < 4; s++) { vals[s] = acc[s][r] + bv4[s]; psum += vals[s]; }
#pragma unroll
    for (int msk = 1; msk < 16; msk <<= 1) psum += __shfl_xor(psum, msk, 64);
    float mean = psum * (1.0f / 64.0f);
    float pvar = 0.f;
#pragma unroll
    for (int s = 0; s < 4; s++) { float dd = vals[s] - mean; pvar += dd * dd; }
#pragma unroll
    for (int msk = 1; msk < 16; msk <<= 1) pvar += __shfl_xor(pvar, msk, 64);
    float rsq = rsqrtf(pvar * (1.0f / 64.0f) + 1e-5f);
    int row = bm + wvid * 16 + (lane >> 4) * 4 + r;
    if (row < NN) {
#pragma unroll
      for (int s = 0; s < 4; s++) {
        int col = s * 16 + (lane & 15);
        float v = vals[s];
        h[(size_t)row * 64 + col] = v;
        hT[(size_t)col * NN + row] = (bf16)v;
        mh[(size_t)row * 64 + col] = (bf16)(g4[s] * (v - mean) * rsq + lb4[s]);
      }
    }
  }
}

// ---------------------------------------------------------------- QKV
__global__ __launch_bounds__(256) void qkv_kernel(const bf16* __restrict__ mh, const bf16* __restrict__ qkvT,
                                                  const float* __restrict__ bqkv,
                                                  bf16* __restrict__ qq, bf16* __restrict__ kv) {
  __shared__ bf16 la[64][72];
  __shared__ bf16 lb[320][72];
  const int bm = blockIdx.x * 64;
  const int lane = threadIdx.x & 63, wvid = threadIdx.x >> 6;
#pragma unroll
  for (int r = 0; r < 2; r++) {
    int slot = threadIdx.x * 2 + r;
    int m = slot >> 3, seg = (slot & 7) * 8;
    int row = bm + m;
    uint4 val = make_uint4(0u, 0u, 0u, 0u);
    if (row < NN) val = *(const uint4*)(mh + (size_t)row * 64 + seg);
    *(uint4*)&la[m][seg] = val;
  }
#pragma unroll
  for (int r = 0; r < 10; r++) {
    int slot = threadIdx.x * 10 + r;
    int n = slot >> 3, seg = (slot & 7) * 8;
    *(uint4*)&lb[n][seg] = *(const uint4*)(qkvT + n * 64 + seg);
  }
  __syncthreads();
  f32x4 acc[20] = {};
#pragma unroll
  for (int ks = 0; ks < 2; ks++) {
    bf16x8 af = *(const bf16x8*)&la[wvid * 16 + (lane & 15)][ks * 32 + (lane >> 4) * 8];
#pragma unroll
    for (int s = 0; s < 20; s++) {
      bf16x8 bfr = *(const bf16x8*)&lb[s * 16 + (lane & 15)][ks * 32 + (lane >> 4) * 8];
      acc[s] = __builtin_amdgcn_mfma_f32_16x16x32_bf16(af, bfr, acc[s], 0, 0, 0);
    }
  }
#pragma unroll
  for (int s = 0; s < 20; s++) {
    int col = s * 16 + (lane & 15);
    float bvv = bqkv[col];
    bf16* dst; int dc, stride;
    if (col < 64)       { dst = qq; dc = col;       stride = 128; }
    else if (col < 128) { dst = kv; dc = col - 64;  stride = 192; }
    else if (col < 192) { dst = qq; dc = col - 64;  stride = 128; }
    else                { dst = kv; dc = col - 128; stride = 192; }
#pragma unroll
    for (int r = 0; r < 4; r++) {
      int row = bm + wvid * 16 + (lane >> 4) * 4 + r;
      if (row < NN) dst[(size_t)row * stride + dc] = (bf16)(acc[s][r] + bvv);
    }
  }
}

// ---------------------------------------------------------------- R1: partial k1^T v, k2^T v (625 blocks, vectorized)
__global__ __launch_bounds__(256) void r1_kernel(const bf16* __restrict__ kv, float* __restrict__ part) {
  int b = blockIdx.x;            // 0..624, rows b*16 .. b*16+15
  int c1 = threadIdx.x & 63, grp = threadIdx.x >> 6;
  int r0 = b * 16;
  float a1[16] = {}, a2[16] = {};
  for (int r = 0; r < 16; r++) {
    const bf16* rowp = kv + (size_t)(r0 + r) * 192;
    float k1 = (float)rowp[c1];
    float k2 = (float)rowp[64 + c1];
    union { uint4 v; bf16 b[8]; } v0, v1;
    v0.v = *(const uint4*)(rowp + 128 + grp * 16);
    v1.v = *(const uint4*)(rowp + 136 + grp * 16);
#pragma unroll
    for (int q = 0; q < 8; q++) {
      float va = (float)v0.b[q], vb = (float)v1.b[q];
      a1[q] += k1 * va; a2[q] += k2 * va;
      a1[8 + q] += k1 * vb; a2[8 + q] += k2 * vb;
    }
  }
  float* p1 = part + (size_t)b * 8192 + (size_t)c1 * 64 + grp * 16;
  float* p2 = p1 + 4096;
#pragma unroll
  for (int q = 0; q < 16; q++) { p1[q] = a1[q]; p2[q] = a2[q]; }
}

// ---------------------------------------------------------------- R2a
__global__ __launch_bounds__(256) void r2a_kernel(const float* __restrict__ part, float* __restrict__ part2) {
  int flat = blockIdx.x * 256 + threadIdx.x;   // 0..8191 = mat*4096 + rem
  int y = blockIdx.y;                           // 0..7
  int b0 = y * 79, b1 = min(625, b0 + 79);
  float s = 0.f;
  for (int b = b0; b < b1; b++) s += part[(size_t)b * 8192 + flat];
  part2[(size_t)flat * 8 + y] = s;
}

// ---------------------------------------------------------------- R2b
__global__ void r2b_kernel(const float* __restrict__ part2, const float* __restrict__ lamb, bf16* __restrict__ Bt) {
  int flat = blockIdx.x * 256 + threadIdx.x;   // mat*4096 + rem
  int mat = flat >> 12, rem = flat & 4095;
  int d = rem >> 6, c = rem & 63;
  f32x4 lo = *(const f32x4*)(part2 + (size_t)flat * 8);
  f32x4 hi = *(const f32x4*)(part2 + (size_t)flat * 8 + 4);
  float s = lo[0] + lo[1] + lo[2] + lo[3] + hi[0] + hi[1] + hi[2] + hi[3];
  float v = mat ? (-lamb[0] * s) : s;
  Bt[c * 128 + mat * 64 + d] = (bf16)v;
}

// ---------------------------------------------------------------- D3 split-K: R2 structure, j-tile 128 (512B granule)
// dpart[sk][c][j] = sum_{i in split} hT[c][i] * u[i][j]
__global__ __launch_bounds__(256) void d3_kernel(const float* __restrict__ u, const bf16* __restrict__ hT,
                                                 float* __restrict__ dpart) {
  __shared__ bf16 la[64][72];    // hT tile [c][i]
  __shared__ bf16 lb[128][72];   // u^T tile [j][i], XOR-swizzled in i
  const int j0 = blockIdx.x * 128;
  const int sk = blockIdx.y;
  const int c0 = sk * DCPS, c1e = min(DCHUNKS, c0 + DCPS);
  const int t = threadIdx.x;
  const int lane = t & 63, wv = t >> 6;
  const int jq = (t & 31) * 4;   // 4 consecutive j per thread
  const int rg = t >> 5;          // 0..7 -> 8 consecutive i rows each
  f32x4 acc[8] = {};
  uint4 aC[2];
  float4 uC[8];
  auto fetchAll = [&](int i0) {
#pragma unroll
    for (int r = 0; r < 2; r++) {
      int slot = t * 2 + r;
      int c = slot >> 3, seg = (slot & 7) * 8;
      int i = i0 + seg;
      if (i + 7 < NN) aC[r] = *(const uint4*)(hT + (size_t)c * NN + i);
      else {
        union { uint4 v; bf16 b[8]; } tu;
#pragma unroll
        for (int q = 0; q < 8; q++) tu.b[q] = (i + q < NN) ? hT[(size_t)c * NN + i + q] : (bf16)0.f;
        aC[r] = tu.v;
      }
    }
    int j = j0 + jq;
#pragma unroll
    for (int q = 0; q < 8; q++) {
      int i = i0 + rg * 8 + q;
      if (i < NN && j + 3 < NN) uC[q] = *(const float4*)(u + (size_t)i * NN + j);
      else if (i < NN) {
        float tmp[4];
#pragma unroll
        for (int q2 = 0; q2 < 4; q2++) tmp[q2] = (j + q2 < NN) ? u[(size_t)i * NN + j + q2] : 0.f;
        uC[q] = make_float4(tmp[0], tmp[1], tmp[2], tmp[3]);
      } else uC[q] = make_float4(0.f, 0.f, 0.f, 0.f);
    }
  };
  auto storeAll = [&]() {
#pragma unroll
    for (int r = 0; r < 2; r++) {
      int slot = t * 2 + r;
      int c = slot >> 3, seg = (slot & 7) * 8;
      *(uint4*)&la[c][seg] = aC[r];
    }
#pragma unroll
    for (int q2 = 0; q2 < 4; q2++) {
      int j = jq + q2;
      int isw = (rg * 8) ^ (((j >> 2) & 3) << 3);
      union { uint4 v; bf16 b[8]; } pk;
#pragma unroll
      for (int q = 0; q < 8; q++) pk.b[q] = (bf16)((const float*)&uC[q])[q2];
      *(uint4*)&lb[j][isw] = pk.v;
    }
  };
  fetchAll(c0 * 64);
  for (int ch = c0; ch < c1e; ch++) {
    storeAll();
    if (ch + 1 < c1e) fetchAll((ch + 1) * 64);
    __syncthreads();
#pragma unroll
    for (int ks = 0; ks < 2; ks++) {
      bf16x8 af = *(const bf16x8*)&la[wv * 16 + (lane & 15)][ks * 32 + (lane >> 4) * 8];
#pragma unroll
      for (int s = 0; s < 8; s++) {
        int j = s * 16 + (lane & 15);
        int ioff = (ks * 32 + (lane >> 4) * 8) ^ (((j >> 2) & 3) << 3);
        bf16x8 bfr = *(const bf16x8*)&lb[j][ioff];
        acc[s] = __builtin_amdgcn_mfma_f32_16x16x32_bf16(af, bfr, acc[s], 0, 0, 0);
      }
    }
    __syncthreads();
  }
#pragma unroll
  for (int s = 0; s < 8; s++) {
    int j = j0 + s * 16 + (lane & 15);
#pragma unroll
    for (int r = 0; r < 4; r++) {
      int c = wv * 16 + (lane >> 4) * 4 + r;
      dpart[((size_t)sk * 64 + c) * DJ + j] = acc[s][r];
    }
  }
}

// ---------------------------------------------------------------- D reduce
__global__ void dred_kernel(const float* __restrict__ dpart, const float* __restrict__ newe,
                            bf16* __restrict__ wutxT) {
  int idx = blockIdx.x * 256 + threadIdx.x;
  int c = idx / 2528;
  int j = (idx - c * 2528) * 4;
  if (c >= 64 || j >= NN) return;
  f32x4 s = {};
  for (int sk = 0; sk < DSPLITS; sk++)
    s += *(const f32x4*)(dpart + ((size_t)sk * 64 + c) * DJ + j);
  union { uint2 w; bf16 b[4]; } pk;
#pragma unroll
  for (int q = 0; q < 4; q++) pk.b[q] = (bf16)(newe[j + q] * s[q]);
  *(uint2*)&wutxT[(size_t)c * NN + j] = pk.w;
}

// ---------------------------------------------------------------- E3 split-K: R2 structure, j-chunk 128 (512B granule)
// epart[sk][i][c] = sum_{j in split} u[i][j] * wutxT[c][j]
__global__ __launch_bounds__(256) void e3_kernel(const float* __restrict__ u, const bf16* __restrict__ wutxT,
                                                 float* __restrict__ epart) {
  __shared__ bf16 la[64][136];   // u rows bf16 [i][j]
  __shared__ bf16 lb[64][136];   // wutxT [c][j]
  const int bm = blockIdx.x * 64;
  const int sk = blockIdx.y;
  const int c0 = sk * ECPS, c1e = min(ECHUNKS, c0 + ECPS);
  const int t = threadIdx.x;
  const int lane = t & 63, wv = t >> 6;
  const int mA = t >> 2, segA = (t & 3) * 32;     // u: row, 32 floats
  const int mrow = bm + mA;
  f32x4 acc[4] = {};
  float4 uC[8];
  uint4 wC[4];
  auto fetchAll = [&](int jc) {
#pragma unroll
    for (int q = 0; q < 8; q++) {
      int j = jc + segA + q * 4;
      if (mrow < NN && j + 3 < NN) uC[q] = *(const float4*)(u + (size_t)mrow * NN + j);
      else if (mrow < NN) {
        float tmp[4];
#pragma unroll
        for (int q2 = 0; q2 < 4; q2++) tmp[q2] = (j + q2 < NN) ? u[(size_t)mrow * NN + j + q2] : 0.f;
        uC[q] = make_float4(tmp[0], tmp[1], tmp[2], tmp[3]);
      } else uC[q] = make_float4(0.f, 0.f, 0.f, 0.f);
    }
#pragma unroll
    for (int q = 0; q < 4; q++) {
      int j = jc + segA + q * 8;
      if (j + 7 < NN) wC[q] = *(const uint4*)(wutxT + (size_t)mA * NN + j);
      else {
        union { uint4 v; bf16 b[8]; } tu;
#pragma unroll
        for (int q2 = 0; q2 < 8; q2++) tu.b[q2] = (j + q2 < NN) ? wutxT[(size_t)mA * NN + j + q2] : (bf16)0.f;
        wC[q] = tu.v;
      }
    }
  };
  auto storeAll = [&]() {
    union { uint4 v[2]; bf16 b[16]; } pk;
#pragma unroll
    for (int h = 0; h < 2; h++) {
#pragma unroll
      for (int q = 0; q < 4; q++)
#pragma unroll
        for (int q2 = 0; q2 < 4; q2++) pk.b[q * 4 + q2] = (bf16)((const float*)&uC[h * 4 + q])[q2];
      *(uint4*)&la[mA][segA + h * 16] = pk.v[0];
      *(uint4*)&la[mA][segA + h * 16 + 8] = pk.v[1];
    }
#pragma unroll
    for (int q = 0; q < 4; q++) *(uint4*)&lb[mA][segA + q * 8] = wC[q];
  };
  fetchAll(c0 * 128);
  for (int ch = c0; ch < c1e; ch++) {
    storeAll();
    if (ch + 1 < c1e) fetchAll((ch + 1) * 128);
    __syncthreads();
#pragma unroll
    for (int kk = 0; kk < 4; kk++) {
      bf16x8 af = *(const bf16x8*)&la[wv * 16 + (lane & 15)][kk * 32 + (lane >> 4) * 8];
#pragma unroll
      for (int s = 0; s < 4; s++) {
        bf16x8 bfr = *(const bf16x8*)&lb[s * 16 + (lane & 15)][kk * 32 + (lane >> 4) * 8];
        acc[s] = __builtin_amdgcn_mfma_f32_16x16x32_bf16(af, bfr, acc[s], 0, 0, 0);
      }
    }
    __syncthreads();
  }
#pragma unroll
  for (int s = 0; s < 4; s++) {
    int c = s * 16 + (lane & 15);
#pragma unroll
    for (int r = 0; r < 4; r++) {
      int i = bm + wv * 16 + (lane >> 4) * 4 + r;
      if (i < J48) epart[((size_t)sk * J48 + i) * 64 + c] = acc[s][r];
    }
  }
}

// ---------------------------------------------------------------- E reduce
__global__ void ered_kernel(const float* __restrict__ epart, float* __restrict__ h_fur) {
  int idx = blockIdx.x * 256 + threadIdx.x;
  if (idx >= NN * 16) return;
  size_t off = (size_t)idx * 4;
  f32x4 s = {};
  for (int sk = 0; sk < ESPLITS; sk++)
    s += *(const f32x4*)(epart + (size_t)sk * (J48 * 64) + off);
  *(f32x4*)(h_fur + off) = s;
}

// ---------------------------------------------------------------- H: xa = qq@Bt ; LN ; *0.8
__global__ __launch_bounds__(256) void hattn_kernel(const bf16* __restrict__ qq, const bf16* __restrict__ Bt,
                                                    const float* __restrict__ g, const float* __restrict__ b,
                                                    bf16* __restrict__ xan) {
  __shared__ bf16 la[64][136];
  __shared__ bf16 lb[64][136];
  const int bm = blockIdx.x * 64;
  const int lane = threadIdx.x & 63, wvid = threadIdx.x >> 6;
#pragma unroll
  for (int r = 0; r < 4; r++) {
    int slot = threadIdx.x * 4 + r;
    int m = slot >> 4, seg = (slot & 15) * 8;
    int row = bm + m;
    uint4 val = make_uint4(0u, 0u, 0u, 0u);
    if (row < NN) val = *(const uint4*)(qq + (size_t)row * 128 + seg);
    *(uint4*)&la[m][seg] = val;
    *(uint4*)&lb[m][seg] = *(const uint4*)(Bt + m * 128 + seg);
  }
  __syncthreads();
  f32x4 acc[4] = {};
#pragma unroll
  for (int ks = 0; ks < 4; ks++) {
    bf16x8 af = *(const bf16x8*)&la[wvid * 16 + (lane & 15)][ks * 32 + (lane >> 4) * 8];
#pragma unroll
    for (int s = 0; s < 4; s++) {
      bf16x8 bfr = *(const bf16x8*)&lb[s * 16 + (lane & 15)][ks * 32 + (lane >> 4) * 8];
      acc[s] = __builtin_amdgcn_mfma_f32_16x16x32_bf16(af, bfr, acc[s], 0, 0, 0);
    }
  }
#pragma unroll
  for (int r = 0; r < 4; r++) {
    float psum = acc[0][r] + acc[1][r] + acc[2][r] + acc[3][r];
#pragma unroll
    for (int msk = 1; msk < 16; msk <<= 1) psum += __shfl_xor(psum, msk, 64);
    float mean = psum * (1.0f / 64.0f);
    float pvar = 0.f;
#pragma unroll
    for (int s = 0; s < 4; s++) { float dd = acc[s][r] - mean; pvar += dd * dd; }
#pragma unroll
    for (int msk = 1; msk < 16; msk <<= 1) pvar += __shfl_xor(pvar, msk, 64);
    float rsq = rsqrtf(pvar * (1.0f / 64.0f) + 1e-5f);
    int row = bm + wvid * 16 + (lane >> 4) * 4 + r;
    if (row < NN) {
#pragma unroll
      for (int s = 0; s < 4; s++) {
        int col = s * 16 + (lane & 15);
        float o = 0.8f * (g[col] * (acc[s][r] - mean) * rsq + b[col]);
        xan[(size_t)row * 64 + col] = (bf16)o;
      }
    }
  }
}

// ---------------------------------------------------------------- final
__global__ __launch_bounds__(256) void final_kernel(const float* __restrict__ h, const float* __restrict__ h_fur,
                                                    const bf16* __restrict__ xan,
                                                    const float* __restrict__ out_w, const float* __restrict__ out_b,
                                                    const float* __restrict__ gg, const float* __restrict__ gb,
                                                    const float* __restrict__ gw, const float* __restrict__ gbias,
                                                    const float* __restrict__ fg, const float* __restrict__ fb,
                                                    const float* __restrict__ fw1, const float* __restrict__ fb1,
                                                    const float* __restrict__ fw2, const float* __restrict__ fb2,
                                                    float* __restrict__ out) {
  __shared__ float s_ow[64][64];
  __shared__ float s_w1[64][64];
  __shared__ float s_w2[64][64];
  __shared__ float s_gw[192][3];
  __shared__ float s_row[4][64];
  const int lane = threadIdx.x & 63, wvid = threadIdx.x >> 6;
  for (int i = threadIdx.x; i < 4096; i += 256) {
    ((float*)s_ow)[i] = out_w[i];
    ((float*)s_w1)[i] = fw1[i];
    ((float*)s_w2)[i] = fw2[i];
  }
  for (int i = threadIdx.x; i < 576; i += 256) ((float*)s_gw)[i] = gw[i];
  const int row = blockIdx.x * 4 + wvid;
  float x_h = h[(size_t)row * 64 + lane];
  float x_f = h_fur[(size_t)row * 64 + lane];
  float x_a = (float)xan[(size_t)row * 64 + lane];
  s_row[wvid][lane] = x_a;
  __syncthreads();
  float mha = out_b[lane];
#pragma unroll 8
  for (int d = 0; d < 64; d++) mha += s_row[wvid][d] * s_ow[d][lane];
  float m3 = wave_sum64(x_h + mha + x_f) * (1.0f / 192.0f);
  float dh = x_h - m3, dm = mha - m3, df = x_f - m3;
  float v3 = wave_sum64(dh * dh + dm * dm + df * df) * (1.0f / 192.0f);
  float rs3 = rsqrtf(v3 + 1e-5f);
  float l0 = gg[lane] * dh * rs3 + gb[lane];
  float l1 = gg[64 + lane] * dm * rs3 + gb[64 + lane];
  float l2 = gg[128 + lane] * df * rs3 + gb[128 + lane];
  float p0 = l0 * s_gw[lane][0] + l1 * s_gw[64 + lane][0] + l2 * s_gw[128 + lane][0];
  float p1 = l0 * s_gw[lane][1] + l1 * s_gw[64 + lane][1] + l2 * s_gw[128 + lane][1];
  float p2 = l0 * s_gw[lane][2] + l1 * s_gw[64 + lane][2] + l2 * s_gw[128 + lane][2];
  p0 = wave_sum64(p0) + gbias[0];
  p1 = wave_sum64(p1) + gbias[1];
  p2 = wave_sum64(p2) + gbias[2];
  float mx = fmaxf(p0, fmaxf(p1, p2));
  float e0 = expf(p0 - mx), e1 = expf(p1 - mx), e2 = expf(p2 - mx);
  float inv = 1.0f / (e0 + e1 + e2);
  float mix = x_h * (e0 * inv) + mha * (e1 * inv) + x_f * (e2 * inv);
  float mf = wave_sum64(mix) * (1.0f / 64.0f);
  float dmx = mix - mf;
  float vf = wave_sum64(dmx * dmx) * (1.0f / 64.0f);
  float f = fg[lane] * dmx * rsqrtf(vf + 1e-5f) + fb[lane];
  __syncthreads();
  s_row[wvid][lane] = f;
  __syncthreads();
  float t1 = fb1[lane];
#pragma unroll 8
  for (int d = 0; d < 64; d++) t1 += s_row[wvid][d] * s_w1[d][lane];
  t1 = 0.5f * t1 * (1.0f + erff(t1 * 0.70710678118654752f));
  __syncthreads();
  s_row[wvid][lane] = t1;
  __syncthreads();
  float f2 = fb2[lane];
#pragma unroll 8
  for (int d = 0; d < 64; d++) f2 += s_row[wvid][d] * s_w2[d][lane];
  out[(size_t)row * 64 + lane] = mix + f2;
}

// ================================================================ launch
extern "C" void kernel_launch(void* const* d_in, const int* in_sizes, int n_in,
                              void* d_out, int out_size, void* d_ws, size_t ws_size,
                              hipStream_t stream) {
  const float* e          = (const float*)d_in[0];
  const float* u          = (const float*)d_in[1];
  const float* x          = (const float*)d_in[2];
  const float* fe_w1      = (const float*)d_in[3];
  const float* fe_b1      = (const float*)d_in[4];
  const float* fe_w2      = (const float*)d_in[5];
  const float* fe_b2      = (const float*)d_in[6];
  const float* freq_deltas= (const float*)d_in[7];
  const float* freq_bias  = (const float*)d_in[8];
  const float* readout_w  = (const float*)d_in[9];
  const float* readout_b  = (const float*)d_in[10];
  const float* alpha_w    = (const float*)d_in[11];
  const float* mha_ln_g   = (const float*)d_in[12];
  const float* mha_ln_b   = (const float*)d_in[13];
  const float* wq1        = (const float*)d_in[14];
  const float* bq1        = (const float*)d_in[15];
  const float* wk1        = (const float*)d_in[16];
  const float* bk1        = (const float*)d_in[17];
  const float* wq2        = (const float*)d_in[18];
  const float* bq2        = (const float*)d_in[19];
  const float* wk2        = (const float*)d_in[20];
  const float* bk2        = (const float*)d_in[21];
  const float* wv_in      = (const float*)d_in[22];
  const float* bv_in      = (const float*)d_in[23];
  const float* lq1        = (const float*)d_in[24];
  const float* lk1        = (const float*)d_in[25];
  const float* lq2        = (const float*)d_in[26];
  const float* lk2        = (const float*)d_in[27];
  const float* attn_ln_g  = (const float*)d_in[28];
  const float* attn_ln_b  = (const float*)d_in[29];
  const float* out_w      = (const float*)d_in[30];
  const float* out_b      = (const float*)d_in[31];
  const float* gate_ln_g  = (const float*)d_in[32];
  const float* gate_ln_b  = (const float*)d_in[33];
  const float* gate_w     = (const float*)d_in[34];
  const float* gate_b     = (const float*)d_in[35];
  const float* ffn_ln_g   = (const float*)d_in[36];
  const float* ffn_ln_b   = (const float*)d_in[37];
  const float* ffn_w1     = (const float*)d_in[38];
  const float* ffn_b1     = (const float*)d_in[39];
  const float* ffn_w2     = (const float*)d_in[40];
  const float* ffn_b2     = (const float*)d_in[41];

  constexpr size_t OFF_H     = 0;               // f32 N*64
  constexpr size_t OFF_T1B   = 2560000;         // bf16 N*128
  constexpr size_t OFF_HT    = 5120000;         // bf16 64*N
  constexpr size_t OFF_MH    = 6400000;         // bf16 N*64
  constexpr size_t OFF_QQ    = 7680000;         // bf16 N*128
  constexpr size_t OFF_KV    = 10240000;        // bf16 N*192
  constexpr size_t OFF_WUTXT = 14080000;        // bf16 64*N
  constexpr size_t OFF_HFUR  = 15360000;        // f32 N*64
  constexpr size_t OFF_XAN   = 17920000;        // bf16 N*64
  constexpr size_t OFF_NEWE  = 19200000;        // f32 N (pad)
  constexpr size_t OFF_BT    = 19240064;        // bf16 64*128
  constexpr size_t OFF_W1T   = 19256448;        // bf16 128*512
  constexpr size_t OFF_W2T   = 19387520;        // bf16 64*128
  constexpr size_t OFF_QKVT  = 19403904;        // bf16 320*64
  constexpr size_t OFF_BQKV  = 19444864;        // f32 320
  constexpr size_t OFF_FREQS = 19446144;        // f32 16
  constexpr size_t OFF_LAM   = 19446208;        // f32 1
  constexpr size_t OFF_BIG   = 19446272;        // shared scratch region
  constexpr size_t OFF_PART2 = OFF_BIG + 20480000;
  constexpr size_t SZ_DPART  = (size_t)DSPLITS * 64 * DJ * 4;  // 41.4 MB
  constexpr size_t WS_NEED   = OFF_BIG + SZ_DPART;
  if (ws_size < WS_NEED) return;

  char* ws = (char*)d_ws;
  float* h_buf   = (float*)(ws + OFF_H);
  bf16*  t1b     = (bf16*)(ws + OFF_T1B);
  bf16*  hT      = (bf16*)(ws + OFF_HT);
  bf16*  mh      = (bf16*)(ws + OFF_MH);
  bf16*  qq      = (bf16*)(ws + OFF_QQ);
  bf16*  kv      = (bf16*)(ws + OFF_KV);
  bf16*  wutxT   = (bf16*)(ws + OFF_WUTXT);
  float* h_fur   = (float*)(ws + OFF_HFUR);
  bf16*  xan     = (bf16*)(ws + OFF_XAN);
  float* newe    = (float*)(ws + OFF_NEWE);
  bf16*  Bt      = (bf16*)(ws + OFF_BT);
  bf16*  w1T     = (bf16*)(ws + OFF_W1T);
  bf16*  w2T     = (bf16*)(ws + OFF_W2T);
  bf16*  qkvT    = (bf16*)(ws + OFF_QKVT);
  float* bqkv    = (float*)(ws + OFF_BQKV);
  float* freqs   = (float*)(ws + OFF_FREQS);
  float* lamb    = (float*)(ws + OFF_LAM);
  float* part    = (float*)(ws + OFF_BIG);      // r1 lifetime
  float* part2   = (float*)(ws + OFF_PART2);    // r2a/r2b lifetime
  float* dpart   = (float*)(ws + OFF_BIG);      // d3/dred lifetime
  float* epart   = (float*)(ws + OFF_BIG);      // e3/ered lifetime

  prep_kernel<<<64, 256, 0, stream>>>(fe_w1, fe_w2, wq1, wk1, wq2, wk2, wv_in,
                                      bq1, bk1, bq2, bk2, bv_in,
                                      lq1, lk1, lq2, lk2, freq_deltas, freq_bias,
                                      w1T, w2T, qkvT, bqkv, freqs, lamb);
  newe_kernel<<<40, 256, 0, stream>>>(e, readout_w, readout_b, alpha_w, freqs, newe);
  g1_kernel<<<157, 256, 0, stream>>>(x, w1T, fe_b1, t1b);
  g2_kernel<<<157, 256, 0, stream>>>(t1b, w2T, fe_b2, mha_ln_g, mha_ln_b, h_buf, hT, mh);
  qkv_kernel<<<157, 256, 0, stream>>>(mh, qkvT, bqkv, qq, kv);
  r1_kernel<<<625, 256, 0, stream>>>(kv, part);
  r2a_kernel<<<dim3(32, 8), 256, 0, stream>>>(part, part2);
  r2b_kernel<<<32, 256, 0, stream>>>(part2, lamb, Bt);
  d3_kernel<<<dim3(79, DSPLITS), 256, 0, stream>>>(u, hT, dpart);
  dred_kernel<<<632, 256, 0, stream>>>(dpart, newe, wutxT);
  e3_kernel<<<dim3(157, ESPLITS), 256, 0, stream>>>(u, wutxT, epart);
  ered_kernel<<<625, 256, 0, stream>>>(epart, h_fur);
  hattn_kernel<<<157, 256, 0, stream>>>(qq, Bt, attn_ln_g, attn_ln_b, xan);
  final_kernel<<<2500, 256, 0, stream>>>(h_buf, h_fur, xan, out_w, out_b,
                                         gate_ln_g, gate_ln_b, gate_w, gate_b,
                                         ffn_ln_g, ffn_ln_b, ffn_w1, ffn_b1, ffn_w2, ffn_b2,
                                         (float*)d_out);
}

// Round 6
// 405.482 us; speedup vs baseline: 1.1579x; 1.1579x over previous
//
#include <hip/hip_runtime.h>
#include <hip/hip_bf16.h>
#include <math.h>

#define NN 10000
#define J48 10048
#define CHUNKS 157
#define CPS 20
#define SPLITS 8

typedef __bf16 bf16;
typedef bf16 bf16x8 __attribute__((ext_vector_type(8)));
typedef float f32x4 __attribute__((ext_vector_type(4)));

__device__ __forceinline__ float wave_sum64(float v) {
#pragma unroll
  for (int m = 32; m >= 1; m >>= 1) v += __shfl_xor(v, m, 64);
  return v;
}

// ---------------------------------------------------------------- prep
__global__ void prep_kernel(const float* __restrict__ w1, const float* __restrict__ w2,
                            const float* __restrict__ wq1, const float* __restrict__ wk1,
                            const float* __restrict__ wq2, const float* __restrict__ wk2,
                            const float* __restrict__ wvw,
                            const float* __restrict__ bq1, const float* __restrict__ bk1,
                            const float* __restrict__ bq2, const float* __restrict__ bk2,
                            const float* __restrict__ bvv,
                            const float* __restrict__ lq1, const float* __restrict__ lk1,
                            const float* __restrict__ lq2, const float* __restrict__ lk2,
                            const float* __restrict__ freq_deltas, const float* __restrict__ freq_bias,
                            bf16* __restrict__ w1T, bf16* __restrict__ w2T, bf16* __restrict__ qkvT,
                            float* __restrict__ bqkv, float* __restrict__ freqs, float* __restrict__ lamb) {
  int tid = blockIdx.x * blockDim.x + threadIdx.x;
  int nthr = gridDim.x * blockDim.x;
  for (int i = tid; i < 512 * 128; i += nthr) {
    int o = i >> 9, k = i & 511;
    w1T[i] = (bf16)w1[k * 128 + o];
  }
  for (int i = tid; i < 64 * 128; i += nthr) {
    int o = i >> 7, k = i & 127;
    w2T[i] = (bf16)w2[k * 64 + o];
  }
  for (int i = tid; i < 320 * 64; i += nthr) {
    int r = i >> 6, k = i & 63;
    const float* W = (r < 64) ? wq1 : (r < 128) ? wk1 : (r < 192) ? wq2 : (r < 256) ? wk2 : wvw;
    qkvT[i] = (bf16)W[k * 64 + (r & 63)];
  }
  for (int i = tid; i < 320; i += nthr) {
    const float* B = (i < 64) ? bq1 : (i < 128) ? bk1 : (i < 192) ? bq2 : (i < 256) ? bk2 : bvv;
    bqkv[i] = B[i & 63];
  }
  if (blockIdx.x == 0) {
    if (threadIdx.x == 0) {
      float acc = freq_bias[0];
      for (int f = 0; f < 16; f++) {
        acc += log1pf(expf(freq_deltas[f])) + 0.25f;
        freqs[f] = 50.0f * tanhf(acc * (1.0f / 50.0f));
      }
    }
    if (threadIdx.x >= 64 && threadIdx.x < 128) {
      int l = threadIdx.x - 64;
      float s1 = wave_sum64(lq1[l] * lk1[l]);
      float s2 = wave_sum64(lq2[l] * lk2[l]);
      if (l == 0) lamb[0] = expf(s1) - expf(s2) + 0.2f;
    }
  }
}

// ---------------------------------------------------------------- new_e
__global__ void newe_kernel(const float* __restrict__ e, const float* __restrict__ rw,
                            const float* __restrict__ rb, const float* __restrict__ aw,
                            const float* __restrict__ freqs, float* __restrict__ newe) {
  int n = blockIdx.x * blockDim.x + threadIdx.x;
  if (n >= NN) return;
  float fr[16];
#pragma unroll
  for (int f = 0; f < 16; f++) fr[f] = freqs[f];
  float ev = e[n], p = 1.0f, acc = 0.0f;
  for (int k = 0; k < 10; k++) {
    p *= ev;
    float s = rb[k] + rw[k * 33];
#pragma unroll
    for (int f = 0; f < 16; f++) {
      float ph = p * fr[f];
      s += 0.25f * (__sinf(ph) * rw[k * 33 + 1 + f] + __cosf(ph) * rw[k * 33 + 17 + f]);
    }
    acc += s * aw[k];
  }
  newe[n] = acc;
}

// ---------------------------------------------------------------- ucopy: u f32 -> bf16 (streaming; 200MB fits L3)
__global__ __launch_bounds__(256) void ucopy_kernel(const float* __restrict__ u, bf16* __restrict__ ubf) {
  size_t base = ((size_t)blockIdx.x * 256 + threadIdx.x) * 8;
  size_t stride = (size_t)gridDim.x * 256 * 8;
  for (size_t i = base; i < (size_t)NN * NN; i += stride) {
    float4 a = *(const float4*)(u + i);
    float4 b = *(const float4*)(u + i + 4);
    union { uint4 v; bf16 h[8]; } pk;
    pk.h[0] = (bf16)a.x; pk.h[1] = (bf16)a.y; pk.h[2] = (bf16)a.z; pk.h[3] = (bf16)a.w;
    pk.h[4] = (bf16)b.x; pk.h[5] = (bf16)b.y; pk.h[6] = (bf16)b.z; pk.h[7] = (bf16)b.w;
    *(uint4*)(ubf + i) = pk.v;
  }
}

// ---------------------------------------------------------------- G1
__global__ __launch_bounds__(256) void g1_kernel(const float* __restrict__ x, const bf16* __restrict__ w1T,
                                                 const float* __restrict__ b1, bf16* __restrict__ t1b) {
  __shared__ bf16 la[64][40];
  __shared__ bf16 lb[128][40];
  const int bm = blockIdx.x * 64;
  const int lane = threadIdx.x & 63, wvid = threadIdx.x >> 6;
  const int am = threadIdx.x >> 2, aseg = (threadIdx.x & 3) * 8;
  const int arow = bm + am;
  f32x4 acc[8] = {};
  float4 aLo, aHi;
  uint4 bChunk[2];
  auto fetchAll = [&](int k0) {
    if (arow < NN) {
      const float4* p = (const float4*)(x + (size_t)arow * 512 + k0 + aseg);
      aLo = p[0]; aHi = p[1];
    } else {
      aLo = make_float4(0.f, 0.f, 0.f, 0.f); aHi = aLo;
    }
#pragma unroll
    for (int r = 0; r < 2; r++) {
      int slot = threadIdx.x * 2 + r;
      int n = slot >> 2, seg = (slot & 3) * 8;
      bChunk[r] = *(const uint4*)(w1T + n * 512 + k0 + seg);
    }
  };
  auto store = [&]() {
    union { uint4 v; bf16 b[8]; } pk;
    float av[8] = {aLo.x, aLo.y, aLo.z, aLo.w, aHi.x, aHi.y, aHi.z, aHi.w};
#pragma unroll
    for (int t = 0; t < 8; t++) pk.b[t] = (bf16)av[t];
    *(uint4*)&la[am][aseg] = pk.v;
#pragma unroll
    for (int r = 0; r < 2; r++) {
      int slot = threadIdx.x * 2 + r;
      int n = slot >> 2, seg = (slot & 3) * 8;
      *(uint4*)&lb[n][seg] = bChunk[r];
    }
  };
  fetchAll(0);
  for (int k0 = 0; k0 < 512; k0 += 32) {
    store();
    if (k0 + 32 < 512) fetchAll(k0 + 32);
    __syncthreads();
    bf16x8 af = *(const bf16x8*)&la[wvid * 16 + (lane & 15)][(lane >> 4) * 8];
#pragma unroll
    for (int s = 0; s < 8; s++) {
      bf16x8 bfr = *(const bf16x8*)&lb[s * 16 + (lane & 15)][(lane >> 4) * 8];
      acc[s] = __builtin_amdgcn_mfma_f32_16x16x32_bf16(af, bfr, acc[s], 0, 0, 0);
    }
    __syncthreads();
  }
#pragma unroll
  for (int s = 0; s < 8; s++) {
    int col = s * 16 + (lane & 15);
    float bvv = b1[col];
#pragma unroll
    for (int r = 0; r < 4; r++) {
      int row = bm + wvid * 16 + (lane >> 4) * 4 + r;
      if (row < NN) {
        float v = acc[s][r] + bvv;
        t1b[(size_t)row * 128 + col] = (bf16)(v > 0.f ? v : 0.f);
      }
    }
  }
}

// ---------------------------------------------------------------- G2 (+ fused mha-LN epilogue)
__global__ __launch_bounds__(256) void g2_kernel(const bf16* __restrict__ t1b, const bf16* __restrict__ w2T,
                                                 const float* __restrict__ b2, const float* __restrict__ lng,
                                                 const float* __restrict__ lnb, float* __restrict__ h,
                                                 bf16* __restrict__ hT, bf16* __restrict__ mh) {
  __shared__ bf16 la[64][72];
  __shared__ bf16 lb[64][72];
  const int bm = blockIdx.x * 64;
  const int lane = threadIdx.x & 63, wvid = threadIdx.x >> 6;
  f32x4 acc[4] = {};
  for (int k0 = 0; k0 < 128; k0 += 64) {
#pragma unroll
    for (int r = 0; r < 2; r++) {
      int slot = threadIdx.x * 2 + r;
      int m = slot >> 3, seg = (slot & 7) * 8;
      int row = bm + m;
      uint4 val = make_uint4(0u, 0u, 0u, 0u);
      if (row < NN) val = *(const uint4*)(t1b + (size_t)row * 128 + k0 + seg);
      *(uint4*)&la[m][seg] = val;
      *(uint4*)&lb[m][seg] = *(const uint4*)(w2T + m * 128 + k0 + seg);
    }
    __syncthreads();
#pragma unroll
    for (int ks = 0; ks < 2; ks++) {
      bf16x8 af = *(const bf16x8*)&la[wvid * 16 + (lane & 15)][ks * 32 + (lane >> 4) * 8];
#pragma unroll
      for (int s = 0; s < 4; s++) {
        bf16x8 bfr = *(const bf16x8*)&lb[s * 16 + (lane & 15)][ks * 32 + (lane >> 4) * 8];
        acc[s] = __builtin_amdgcn_mfma_f32_16x16x32_bf16(af, bfr, acc[s], 0, 0, 0);
      }
    }
    __syncthreads();
  }
  float bv4[4], g4[4], lb4[4];
#pragma unroll
  for (int s = 0; s < 4; s++) {
    int col = s * 16 + (lane & 15);
    bv4[s] = b2[col]; g4[s] = lng[col]; lb4[s] = lnb[col];
  }
#pragma unroll
  for (int r = 0; r < 4; r++) {
    float vals[4], psum = 0.f;
#pragma unroll
    for (int s = 0; s < 4; s++) { vals[s] = acc[s][r] + bv4[s]; psum += vals[s]; }
#pragma unroll
    for (int msk = 1; msk < 16; msk <<= 1) psum += __shfl_xor(psum, msk, 64);
    float mean = psum * (1.0f / 64.0f);
    float pvar = 0.f;
#pragma unroll
    for (int s = 0; s < 4; s++) { float dd = vals[s] - mean; pvar += dd * dd; }
#pragma unroll
    for (int msk = 1; msk < 16; msk <<= 1) pvar += __shfl_xor(pvar, msk, 64);
    float rsq = rsqrtf(pvar * (1.0f / 64.0f) + 1e-5f);
    int row = bm + wvid * 16 + (lane >> 4) * 4 + r;
    if (row < NN) {
#pragma unroll
      for (int s = 0; s < 4; s++) {
        int col = s * 16 + (lane & 15);
        float v = vals[s];
        h[(size_t)row * 64 + col] = v;
        hT[(size_t)col * NN + row] = (bf16)v;
        mh[(size_t)row * 64 + col] = (bf16)(g4[s] * (v - mean) * rsq + lb4[s]);
      }
    }
  }
}

// ---------------------------------------------------------------- QKV
__global__ __launch_bounds__(256) void qkv_kernel(const bf16* __restrict__ mh, const bf16* __restrict__ qkvT,
                                                  const float* __restrict__ bqkv,
                                                  bf16* __restrict__ qq, bf16* __restrict__ kv) {
  __shared__ bf16 la[64][72];
  __shared__ bf16 lb[320][72];
  const int bm = blockIdx.x * 64;
  const int lane = threadIdx.x & 63, wvid = threadIdx.x >> 6;
#pragma unroll
  for (int r = 0; r < 2; r++) {
    int slot = threadIdx.x * 2 + r;
    int m = slot >> 3, seg = (slot & 7) * 8;
    int row = bm + m;
    uint4 val = make_uint4(0u, 0u, 0u, 0u);
    if (row < NN) val = *(const uint4*)(mh + (size_t)row * 64 + seg);
    *(uint4*)&la[m][seg] = val;
  }
#pragma unroll
  for (int r = 0; r < 10; r++) {
    int slot = threadIdx.x * 10 + r;
    int n = slot >> 3, seg = (slot & 7) * 8;
    *(uint4*)&lb[n][seg] = *(const uint4*)(qkvT + n * 64 + seg);
  }
  __syncthreads();
  f32x4 acc[20] = {};
#pragma unroll
  for (int ks = 0; ks < 2; ks++) {
    bf16x8 af = *(const bf16x8*)&la[wvid * 16 + (lane & 15)][ks * 32 + (lane >> 4) * 8];
#pragma unroll
    for (int s = 0; s < 20; s++) {
      bf16x8 bfr = *(const bf16x8*)&lb[s * 16 + (lane & 15)][ks * 32 + (lane >> 4) * 8];
      acc[s] = __builtin_amdgcn_mfma_f32_16x16x32_bf16(af, bfr, acc[s], 0, 0, 0);
    }
  }
#pragma unroll
  for (int s = 0; s < 20; s++) {
    int col = s * 16 + (lane & 15);
    float bvv = bqkv[col];
    bf16* dst; int dc, stride;
    if (col < 64)       { dst = qq; dc = col;       stride = 128; }
    else if (col < 128) { dst = kv; dc = col - 64;  stride = 192; }
    else if (col < 192) { dst = qq; dc = col - 64;  stride = 128; }
    else                { dst = kv; dc = col - 128; stride = 192; }
#pragma unroll
    for (int r = 0; r < 4; r++) {
      int row = bm + wvid * 16 + (lane >> 4) * 4 + r;
      if (row < NN) dst[(size_t)row * stride + dc] = (bf16)(acc[s][r] + bvv);
    }
  }
}

// ---------------------------------------------------------------- R1
__global__ __launch_bounds__(256) void r1_kernel(const bf16* __restrict__ kv, float* __restrict__ part) {
  int b = blockIdx.x;            // 0..624, rows b*16 .. b*16+15
  int c1 = threadIdx.x & 63, grp = threadIdx.x >> 6;
  int r0 = b * 16;
  float a1[16] = {}, a2[16] = {};
  for (int r = 0; r < 16; r++) {
    const bf16* rowp = kv + (size_t)(r0 + r) * 192;
    float k1 = (float)rowp[c1];
    float k2 = (float)rowp[64 + c1];
    union { uint4 v; bf16 b[8]; } v0, v1;
    v0.v = *(const uint4*)(rowp + 128 + grp * 16);
    v1.v = *(const uint4*)(rowp + 136 + grp * 16);
#pragma unroll
    for (int q = 0; q < 8; q++) {
      float va = (float)v0.b[q], vb = (float)v1.b[q];
      a1[q] += k1 * va; a2[q] += k2 * va;
      a1[8 + q] += k1 * vb; a2[8 + q] += k2 * vb;
    }
  }
  float* p1 = part + (size_t)b * 8192 + (size_t)c1 * 64 + grp * 16;
  float* p2 = p1 + 4096;
#pragma unroll
  for (int q = 0; q < 16; q++) { p1[q] = a1[q]; p2[q] = a2[q]; }
}

// ---------------------------------------------------------------- R2a
__global__ __launch_bounds__(256) void r2a_kernel(const float* __restrict__ part, float* __restrict__ part2) {
  int flat = blockIdx.x * 256 + threadIdx.x;
  int y = blockIdx.y;
  int b0 = y * 79, b1 = min(625, b0 + 79);
  float s = 0.f;
  for (int b = b0; b < b1; b++) s += part[(size_t)b * 8192 + flat];
  part2[(size_t)flat * 8 + y] = s;
}

// ---------------------------------------------------------------- R2b
__global__ void r2b_kernel(const float* __restrict__ part2, const float* __restrict__ lamb, bf16* __restrict__ Bt) {
  int flat = blockIdx.x * 256 + threadIdx.x;
  int mat = flat >> 12, rem = flat & 4095;
  int d = rem >> 6, c = rem & 63;
  f32x4 lo = *(const f32x4*)(part2 + (size_t)flat * 8);
  f32x4 hi = *(const f32x4*)(part2 + (size_t)flat * 8 + 4);
  float s = lo[0] + lo[1] + lo[2] + lo[3] + hi[0] + hi[1] + hi[2] + hi[3];
  float v = mat ? (-lamb[0] * s) : s;
  Bt[c * 128 + mat * 64 + d] = (bf16)v;
}

// ---------------------------------------------------------------- D split-K (R2 structure, bf16 u)
// dpart[sk][c][j] = sum_{i in split} hT[c][i] * ubf[i][j]
__global__ __launch_bounds__(256) void d_split_kernel(const bf16* __restrict__ ubf, const bf16* __restrict__ hT,
                                                      float* __restrict__ dpart) {
  __shared__ bf16 la[64][72];   // hT tile [c][i]
  __shared__ bf16 lb[64][72];   // u^T tile [j][i], XOR-swizzled in i
  const int j0 = blockIdx.x * 64;
  const int sk = blockIdx.y;
  const int c0 = sk * CPS, c1e = min(CHUNKS, c0 + CPS);
  const int t = threadIdx.x;
  const int lane = t & 63, wv = t >> 6;
  const int jl = (t & 15) * 4;
  const int ir = (t >> 4) * 4;
  f32x4 acc[4] = {};
  uint4 aC[2];
  uint2 uc[4];
  auto fetchAll = [&](int i0) {
#pragma unroll
    for (int r = 0; r < 2; r++) {
      int slot = t * 2 + r;
      int c = slot >> 3, seg = (slot & 7) * 8;
      int i = i0 + seg;
      if (i + 7 < NN) aC[r] = *(const uint4*)(hT + (size_t)c * NN + i);
      else {
        union { uint4 v; bf16 b[8]; } tu;
#pragma unroll
        for (int q = 0; q < 8; q++) tu.b[q] = (i + q < NN) ? hT[(size_t)c * NN + i + q] : (bf16)0.f;
        aC[r] = tu.v;
      }
    }
#pragma unroll
    for (int q = 0; q < 4; q++) {
      int i = i0 + ir + q;
      if (i < NN && (j0 + jl + 3) < NN) uc[q] = *(const uint2*)(ubf + (size_t)i * NN + j0 + jl);
      else if (i < NN) {
        union { uint2 w; bf16 b[4]; } tu;
#pragma unroll
        for (int q2 = 0; q2 < 4; q2++) tu.b[q2] = (j0 + jl + q2 < NN) ? ubf[(size_t)i * NN + j0 + jl + q2] : (bf16)0.f;
        uc[q] = tu.w;
      } else uc[q] = make_uint2(0u, 0u);
    }
  };
  auto storeAll = [&]() {
#pragma unroll
    for (int r = 0; r < 2; r++) {
      int slot = t * 2 + r;
      int c = slot >> 3, seg = (slot & 7) * 8;
      *(uint4*)&la[c][seg] = aC[r];
    }
#pragma unroll
    for (int q2 = 0; q2 < 4; q2++) {
      int j = jl + q2;
      int isw = ir ^ (((j >> 2) & 3) << 3);
      union { uint2 w; bf16 b[4]; } pk;
      pk.b[0] = ((const bf16*)&uc[0])[q2];
      pk.b[1] = ((const bf16*)&uc[1])[q2];
      pk.b[2] = ((const bf16*)&uc[2])[q2];
      pk.b[3] = ((const bf16*)&uc[3])[q2];
      *(uint2*)&lb[j][isw] = pk.w;
    }
  };
  fetchAll(c0 * 64);
  for (int ch = c0; ch < c1e; ch++) {
    storeAll();
    if (ch + 1 < c1e) fetchAll((ch + 1) * 64);
    __syncthreads();
#pragma unroll
    for (int ks = 0; ks < 2; ks++) {
      bf16x8 af = *(const bf16x8*)&la[wv * 16 + (lane & 15)][ks * 32 + (lane >> 4) * 8];
#pragma unroll
      for (int s = 0; s < 4; s++) {
        int j = s * 16 + (lane & 15);
        int ioff = (ks * 32 + (lane >> 4) * 8) ^ (((j >> 2) & 3) << 3);
        bf16x8 bfr = *(const bf16x8*)&lb[j][ioff];
        acc[s] = __builtin_amdgcn_mfma_f32_16x16x32_bf16(af, bfr, acc[s], 0, 0, 0);
      }
    }
    __syncthreads();
  }
#pragma unroll
  for (int s = 0; s < 4; s++) {
    int j = j0 + s * 16 + (lane & 15);
#pragma unroll
    for (int r = 0; r < 4; r++) {
      int c = wv * 16 + (lane >> 4) * 4 + r;
      dpart[((size_t)sk * 64 + c) * J48 + j] = acc[s][r];
    }
  }
}

// ---------------------------------------------------------------- D reduce
__global__ void dred_kernel(const float* __restrict__ dpart, const float* __restrict__ newe,
                            bf16* __restrict__ wutxT) {
  int idx = blockIdx.x * 256 + threadIdx.x;
  int c = idx / 2512;
  int j = (idx - c * 2512) * 4;
  if (c >= 64 || j >= NN) return;
  f32x4 s = {};
  for (int sk = 0; sk < SPLITS; sk++)
    s += *(const f32x4*)(dpart + ((size_t)sk * 64 + c) * J48 + j);
  union { uint2 w; bf16 b[4]; } pk;
#pragma unroll
  for (int q = 0; q < 4; q++) pk.b[q] = (bf16)(newe[j + q] * s[q]);
  *(uint2*)&wutxT[(size_t)c * NN + j] = pk.w;
}

// ---------------------------------------------------------------- E split-K (R2 structure, bf16 u)
// epart[sk][i][c] = sum_{j in split} ubf[i][j] * wutxT[c][j]
__global__ __launch_bounds__(256) void e_split_kernel(const bf16* __restrict__ ubf, const bf16* __restrict__ wutxT,
                                                      float* __restrict__ epart) {
  __shared__ bf16 la[64][72];   // u rows [i_local][j]
  __shared__ bf16 lb[64][72];   // wutxT [c][j]
  const int bm = blockIdx.x * 64;
  const int sk = blockIdx.y;
  const int c0 = sk * CPS, c1e = min(CHUNKS, c0 + CPS);
  const int t = threadIdx.x;
  const int lane = t & 63, wv = t >> 6;
  const int mA = t >> 2, segA = (t & 3) * 16;
  const int mrow = bm + mA;
  f32x4 acc[4] = {};
  uint4 aU[2];
  uint4 bC[2];
  auto fetchAll = [&](int j0) {
    int j = j0 + segA;
    if (mrow < NN && j + 15 < NN) {
      aU[0] = *(const uint4*)(ubf + (size_t)mrow * NN + j);
      aU[1] = *(const uint4*)(ubf + (size_t)mrow * NN + j + 8);
    } else {
      union { uint4 v[2]; bf16 b[16]; } tu;
#pragma unroll
      for (int q = 0; q < 16; q++)
        tu.b[q] = (mrow < NN && j + q < NN) ? ubf[(size_t)mrow * NN + j + q] : (bf16)0.f;
      aU[0] = tu.v[0]; aU[1] = tu.v[1];
    }
#pragma unroll
    for (int r = 0; r < 2; r++) {
      int slot = t * 2 + r;
      int c = slot >> 3, seg = (slot & 7) * 8;
      int jj = j0 + seg;
      if (jj + 7 < NN) bC[r] = *(const uint4*)(wutxT + (size_t)c * NN + jj);
      else {
        union { uint4 v; bf16 b[8]; } tu;
#pragma unroll
        for (int q = 0; q < 8; q++) tu.b[q] = (jj + q < NN) ? wutxT[(size_t)c * NN + jj + q] : (bf16)0.f;
        bC[r] = tu.v;
      }
    }
  };
  auto storeAll = [&]() {
    *(uint4*)&la[mA][segA] = aU[0];
    *(uint4*)&la[mA][segA + 8] = aU[1];
#pragma unroll
    for (int r = 0; r < 2; r++) {
      int slot = t * 2 + r;
      int c = slot >> 3, seg = (slot & 7) * 8;
      *(uint4*)&lb[c][seg] = bC[r];
    }
  };
  fetchAll(c0 * 64);
  for (int ch = c0; ch < c1e; ch++) {
    storeAll();
    if (ch + 1 < c1e) fetchAll((ch + 1) * 64);
    __syncthreads();
#pragma unroll
    for (int ks = 0; ks < 2; ks++) {
      bf16x8 af = *(const bf16x8*)&la[wv * 16 + (lane & 15)][ks * 32 + (lane >> 4) * 8];
#pragma unroll
      for (int s = 0; s < 4; s++) {
        bf16x8 bfr = *(const bf16x8*)&lb[s * 16 + (lane & 15)][ks * 32 + (lane >> 4) * 8];
        acc[s] = __builtin_amdgcn_mfma_f32_16x16x32_bf16(af, bfr, acc[s], 0, 0, 0);
      }
    }
    __syncthreads();
  }
#pragma unroll
  for (int s = 0; s < 4; s++) {
    int col = s * 16 + (lane & 15);
#pragma unroll
    for (int r = 0; r < 4; r++) {
      int row = wv * 16 + (lane >> 4) * 4 + r;
      epart[((size_t)sk * J48 + bm + row) * 64 + col] = acc[s][r];
    }
  }
}

// ---------------------------------------------------------------- E reduce
__global__ void ered_kernel(const float* __restrict__ epart, float* __restrict__ h_fur) {
  int idx = blockIdx.x * 256 + threadIdx.x;
  if (idx >= NN * 16) return;
  size_t off = (size_t)idx * 4;
  f32x4 s = {};
  for (int sk = 0; sk < SPLITS; sk++)
    s += *(const f32x4*)(epart + (size_t)sk * (J48 * 64) + off);
  *(f32x4*)(h_fur + off) = s;
}

// ---------------------------------------------------------------- H: xa = qq@Bt ; LN ; *0.8
__global__ __launch_bounds__(256) void hattn_kernel(const bf16* __restrict__ qq, const bf16* __restrict__ Bt,
                                                    const float* __restrict__ g, const float* __restrict__ b,
                                                    bf16* __restrict__ xan) {
  __shared__ bf16 la[64][136];
  __shared__ bf16 lb[64][136];
  const int bm = blockIdx.x * 64;
  const int lane = threadIdx.x & 63, wvid = threadIdx.x >> 6;
#pragma unroll
  for (int r = 0; r < 4; r++) {
    int slot = threadIdx.x * 4 + r;
    int m = slot >> 4, seg = (slot & 15) * 8;
    int row = bm + m;
    uint4 val = make_uint4(0u, 0u, 0u, 0u);
    if (row < NN) val = *(const uint4*)(qq + (size_t)row * 128 + seg);
    *(uint4*)&la[m][seg] = val;
    *(uint4*)&lb[m][seg] = *(const uint4*)(Bt + m * 128 + seg);
  }
  __syncthreads();
  f32x4 acc[4] = {};
#pragma unroll
  for (int ks = 0; ks < 4; ks++) {
    bf16x8 af = *(const bf16x8*)&la[wvid * 16 + (lane & 15)][ks * 32 + (lane >> 4) * 8];
#pragma unroll
    for (int s = 0; s < 4; s++) {
      bf16x8 bfr = *(const bf16x8*)&lb[s * 16 + (lane & 15)][ks * 32 + (lane >> 4) * 8];
      acc[s] = __builtin_amdgcn_mfma_f32_16x16x32_bf16(af, bfr, acc[s], 0, 0, 0);
    }
  }
#pragma unroll
  for (int r = 0; r < 4; r++) {
    float psum = acc[0][r] + acc[1][r] + acc[2][r] + acc[3][r];
#pragma unroll
    for (int msk = 1; msk < 16; msk <<= 1) psum += __shfl_xor(psum, msk, 64);
    float mean = psum * (1.0f / 64.0f);
    float pvar = 0.f;
#pragma unroll
    for (int s = 0; s < 4; s++) { float dd = acc[s][r] - mean; pvar += dd * dd; }
#pragma unroll
    for (int msk = 1; msk < 16; msk <<= 1) pvar += __shfl_xor(pvar, msk, 64);
    float rsq = rsqrtf(pvar * (1.0f / 64.0f) + 1e-5f);
    int row = bm + wvid * 16 + (lane >> 4) * 4 + r;
    if (row < NN) {
#pragma unroll
      for (int s = 0; s < 4; s++) {
        int col = s * 16 + (lane & 15);
        float o = 0.8f * (g[col] * (acc[s][r] - mean) * rsq + b[col]);
        xan[(size_t)row * 64 + col] = (bf16)o;
      }
    }
  }
}

// ---------------------------------------------------------------- final
__global__ __launch_bounds__(256) void final_kernel(const float* __restrict__ h, const float* __restrict__ h_fur,
                                                    const bf16* __restrict__ xan,
                                                    const float* __restrict__ out_w, const float* __restrict__ out_b,
                                                    const float* __restrict__ gg, const float* __restrict__ gb,
                                                    const float* __restrict__ gw, const float* __restrict__ gbias,
                                                    const float* __restrict__ fg, const float* __restrict__ fb,
                                                    const float* __restrict__ fw1, const float* __restrict__ fb1,
                                                    const float* __restrict__ fw2, const float* __restrict__ fb2,
                                                    float* __restrict__ out) {
  __shared__ float s_ow[64][64];
  __shared__ float s_w1[64][64];
  __shared__ float s_w2[64][64];
  __shared__ float s_gw[192][3];
  __shared__ float s_row[4][64];
  const int lane = threadIdx.x & 63, wvid = threadIdx.x >> 6;
  for (int i = threadIdx.x; i < 4096; i += 256) {
    ((float*)s_ow)[i] = out_w[i];
    ((float*)s_w1)[i] = fw1[i];
    ((float*)s_w2)[i] = fw2[i];
  }
  for (int i = threadIdx.x; i < 576; i += 256) ((float*)s_gw)[i] = gw[i];
  const int row = blockIdx.x * 4 + wvid;
  float x_h = h[(size_t)row * 64 + lane];
  float x_f = h_fur[(size_t)row * 64 + lane];
  float x_a = (float)xan[(size_t)row * 64 + lane];
  s_row[wvid][lane] = x_a;
  __syncthreads();
  float mha = out_b[lane];
#pragma unroll 8
  for (int d = 0; d < 64; d++) mha += s_row[wvid][d] * s_ow[d][lane];
  float m3 = wave_sum64(x_h + mha + x_f) * (1.0f / 192.0f);
  float dh = x_h - m3, dm = mha - m3, df = x_f - m3;
  float v3 = wave_sum64(dh * dh + dm * dm + df * df) * (1.0f / 192.0f);
  float rs3 = rsqrtf(v3 + 1e-5f);
  float l0 = gg[lane] * dh * rs3 + gb[lane];
  float l1 = gg[64 + lane] * dm * rs3 + gb[64 + lane];
  float l2 = gg[128 + lane] * df * rs3 + gb[128 + lane];
  float p0 = l0 * s_gw[lane][0] + l1 * s_gw[64 + lane][0] + l2 * s_gw[128 + lane][0];
  float p1 = l0 * s_gw[lane][1] + l1 * s_gw[64 + lane][1] + l2 * s_gw[128 + lane][1];
  float p2 = l0 * s_gw[lane][2] + l1 * s_gw[64 + lane][2] + l2 * s_gw[128 + lane][2];
  p0 = wave_sum64(p0) + gbias[0];
  p1 = wave_sum64(p1) + gbias[1];
  p2 = wave_sum64(p2) + gbias[2];
  float mx = fmaxf(p0, fmaxf(p1, p2));
  float e0 = expf(p0 - mx), e1 = expf(p1 - mx), e2 = expf(p2 - mx);
  float inv = 1.0f / (e0 + e1 + e2);
  float mix = x_h * (e0 * inv) + mha * (e1 * inv) + x_f * (e2 * inv);
  float mf = wave_sum64(mix) * (1.0f / 64.0f);
  float dmx = mix - mf;
  float vf = wave_sum64(dmx * dmx) * (1.0f / 64.0f);
  float f = fg[lane] * dmx * rsqrtf(vf + 1e-5f) + fb[lane];
  __syncthreads();
  s_row[wvid][lane] = f;
  __syncthreads();
  float t1 = fb1[lane];
#pragma unroll 8
  for (int d = 0; d < 64; d++) t1 += s_row[wvid][d] * s_w1[d][lane];
  t1 = 0.5f * t1 * (1.0f + erff(t1 * 0.70710678118654752f));
  __syncthreads();
  s_row[wvid][lane] = t1;
  __syncthreads();
  float f2 = fb2[lane];
#pragma unroll 8
  for (int d = 0; d < 64; d++) f2 += s_row[wvid][d] * s_w2[d][lane];
  out[(size_t)row * 64 + lane] = mix + f2;
}

// ================================================================ launch
extern "C" void kernel_launch(void* const* d_in, const int* in_sizes, int n_in,
                              void* d_out, int out_size, void* d_ws, size_t ws_size,
                              hipStream_t stream) {
  const float* e          = (const float*)d_in[0];
  const float* u          = (const float*)d_in[1];
  const float* x          = (const float*)d_in[2];
  const float* fe_w1      = (const float*)d_in[3];
  const float* fe_b1      = (const float*)d_in[4];
  const float* fe_w2      = (const float*)d_in[5];
  const float* fe_b2      = (const float*)d_in[6];
  const float* freq_deltas= (const float*)d_in[7];
  const float* freq_bias  = (const float*)d_in[8];
  const float* readout_w  = (const float*)d_in[9];
  const float* readout_b  = (const float*)d_in[10];
  const float* alpha_w    = (const float*)d_in[11];
  const float* mha_ln_g   = (const float*)d_in[12];
  const float* mha_ln_b   = (const float*)d_in[13];
  const float* wq1        = (const float*)d_in[14];
  const float* bq1        = (const float*)d_in[15];
  const float* wk1        = (const float*)d_in[16];
  const float* bk1        = (const float*)d_in[17];
  const float* wq2        = (const float*)d_in[18];
  const float* bq2        = (const float*)d_in[19];
  const float* wk2        = (const float*)d_in[20];
  const float* bk2        = (const float*)d_in[21];
  const float* wv_in      = (const float*)d_in[22];
  const float* bv_in      = (const float*)d_in[23];
  const float* lq1        = (const float*)d_in[24];
  const float* lk1        = (const float*)d_in[25];
  const float* lq2        = (const float*)d_in[26];
  const float* lk2        = (const float*)d_in[27];
  const float* attn_ln_g  = (const float*)d_in[28];
  const float* attn_ln_b  = (const float*)d_in[29];
  const float* out_w      = (const float*)d_in[30];
  const float* out_b      = (const float*)d_in[31];
  const float* gate_ln_g  = (const float*)d_in[32];
  const float* gate_ln_b  = (const float*)d_in[33];
  const float* gate_w     = (const float*)d_in[34];
  const float* gate_b     = (const float*)d_in[35];
  const float* ffn_ln_g   = (const float*)d_in[36];
  const float* ffn_ln_b   = (const float*)d_in[37];
  const float* ffn_w1     = (const float*)d_in[38];
  const float* ffn_b1     = (const float*)d_in[39];
  const float* ffn_w2     = (const float*)d_in[40];
  const float* ffn_b2     = (const float*)d_in[41];

  constexpr size_t OFF_H     = 0;               // f32 N*64
  constexpr size_t OFF_T1B   = 2560000;         // bf16 N*128
  constexpr size_t OFF_HT    = 5120000;         // bf16 64*N
  constexpr size_t OFF_MH    = 6400000;         // bf16 N*64
  constexpr size_t OFF_QQ    = 7680000;         // bf16 N*128
  constexpr size_t OFF_KV    = 10240000;        // bf16 N*192
  constexpr size_t OFF_WUTXT = 14080000;        // bf16 64*N
  constexpr size_t OFF_HFUR  = 15360000;        // f32 N*64
  constexpr size_t OFF_XAN   = 17920000;        // bf16 N*64
  constexpr size_t OFF_NEWE  = 19200000;        // f32 N (pad)
  constexpr size_t OFF_BT    = 19240064;        // bf16 64*128
  constexpr size_t OFF_W1T   = 19256448;        // bf16 128*512
  constexpr size_t OFF_W2T   = 19387520;        // bf16 64*128
  constexpr size_t OFF_QKVT  = 19403904;        // bf16 320*64
  constexpr size_t OFF_BQKV  = 19444864;        // f32 320
  constexpr size_t OFF_FREQS = 19446144;        // f32 16
  constexpr size_t OFF_LAM   = 19446208;        // f32 1
  constexpr size_t OFF_BIG   = 19446272;        // part(20.48MB) / dpart / epart (20.58MB) alias
  constexpr size_t SZ_SPART  = (size_t)SPLITS * 64 * J48 * 4;   // 20,578,304
  constexpr size_t OFF_PART2 = OFF_BIG + SZ_SPART;              // 256 KB (r2a/r2b lifetime)
  constexpr size_t OFF_UBF   = OFF_PART2 + 262144;              // bf16 N*N = 200 MB
  constexpr size_t WS_NEED   = OFF_UBF + (size_t)NN * NN * 2;
  if (ws_size < WS_NEED) return;

  char* ws = (char*)d_ws;
  float* h_buf   = (float*)(ws + OFF_H);
  bf16*  t1b     = (bf16*)(ws + OFF_T1B);
  bf16*  hT      = (bf16*)(ws + OFF_HT);
  bf16*  mh      = (bf16*)(ws + OFF_MH);
  bf16*  qq      = (bf16*)(ws + OFF_QQ);
  bf16*  kv      = (bf16*)(ws + OFF_KV);
  bf16*  wutxT   = (bf16*)(ws + OFF_WUTXT);
  float* h_fur   = (float*)(ws + OFF_HFUR);
  bf16*  xan     = (bf16*)(ws + OFF_XAN);
  float* newe    = (float*)(ws + OFF_NEWE);
  bf16*  Bt      = (bf16*)(ws + OFF_BT);
  bf16*  w1T     = (bf16*)(ws + OFF_W1T);
  bf16*  w2T     = (bf16*)(ws + OFF_W2T);
  bf16*  qkvT    = (bf16*)(ws + OFF_QKVT);
  float* bqkv    = (float*)(ws + OFF_BQKV);
  float* freqs   = (float*)(ws + OFF_FREQS);
  float* lamb    = (float*)(ws + OFF_LAM);
  float* part    = (float*)(ws + OFF_BIG);      // r1 lifetime
  float* part2   = (float*)(ws + OFF_PART2);    // r2a/r2b lifetime
  float* dpart   = (float*)(ws + OFF_BIG);      // d/dred lifetime (aliases part)
  float* epart   = (float*)(ws + OFF_BIG);      // e/ered lifetime
  bf16*  ubf     = (bf16*)(ws + OFF_UBF);       // bf16 copy of u (L3-resident)

  prep_kernel<<<64, 256, 0, stream>>>(fe_w1, fe_w2, wq1, wk1, wq2, wk2, wv_in,
                                      bq1, bk1, bq2, bk2, bv_in,
                                      lq1, lk1, lq2, lk2, freq_deltas, freq_bias,
                                      w1T, w2T, qkvT, bqkv, freqs, lamb);
  newe_kernel<<<40, 256, 0, stream>>>(e, readout_w, readout_b, alpha_w, freqs, newe);
  g1_kernel<<<157, 256, 0, stream>>>(x, w1T, fe_b1, t1b);
  g2_kernel<<<157, 256, 0, stream>>>(t1b, w2T, fe_b2, mha_ln_g, mha_ln_b, h_buf, hT, mh);
  qkv_kernel<<<157, 256, 0, stream>>>(mh, qkvT, bqkv, qq, kv);
  r1_kernel<<<625, 256, 0, stream>>>(kv, part);
  r2a_kernel<<<dim3(32, 8), 256, 0, stream>>>(part, part2);
  r2b_kernel<<<32, 256, 0, stream>>>(part2, lamb, Bt);
  ucopy_kernel<<<2048, 256, 0, stream>>>(u, ubf);
  d_split_kernel<<<dim3(157, SPLITS), 256, 0, stream>>>(ubf, hT, dpart);
  dred_kernel<<<628, 256, 0, stream>>>(dpart, newe, wutxT);
  e_split_kernel<<<dim3(157, SPLITS), 256, 0, stream>>>(ubf, wutxT, epart);
  ered_kernel<<<625, 256, 0, stream>>>(epart, h_fur);
  hattn_kernel<<<157, 256, 0, stream>>>(qq, Bt, attn_ln_g, attn_ln_b, xan);
  final_kernel<<<2500, 256, 0, stream>>>(h_buf, h_fur, xan, out_w, out_b,
                                         gate_ln_g, gate_ln_b, gate_w, gate_b,
                                         ffn_ln_g, ffn_ln_b, ffn_w1, ffn_b1, ffn_w2, ffn_b2,
                                         (float*)d_out);
}

// Round 7
// 361.142 us; speedup vs baseline: 1.3001x; 1.1228x over previous
//
#include <hip/hip_runtime.h>
#include <hip/hip_bf16.h>
#include <math.h>

#define NN 10000
#define J48 10048
#define CHUNKS 157
#define CPS 20
#define SPLITS 8

typedef __bf16 bf16;
typedef bf16 bf16x8 __attribute__((ext_vector_type(8)));
typedef float f32x4 __attribute__((ext_vector_type(4)));

// Raw barrier WITHOUT the __syncthreads vmcnt(0) drain: waits only LDS ops,
// leaves register-destined global loads in flight across the barrier.
#define SYNC_LDS() do {                                      \
    asm volatile("s_waitcnt lgkmcnt(0)" ::: "memory");       \
    __builtin_amdgcn_sched_barrier(0);                       \
    __builtin_amdgcn_s_barrier();                            \
    __builtin_amdgcn_sched_barrier(0);                       \
  } while (0)

__device__ __forceinline__ float wave_sum64(float v) {
#pragma unroll
  for (int m = 32; m >= 1; m >>= 1) v += __shfl_xor(v, m, 64);
  return v;
}

// ---------------------------------------------------------------- prep
__global__ void prep_kernel(const float* __restrict__ w1, const float* __restrict__ w2,
                            const float* __restrict__ wq1, const float* __restrict__ wk1,
                            const float* __restrict__ wq2, const float* __restrict__ wk2,
                            const float* __restrict__ wvw,
                            const float* __restrict__ bq1, const float* __restrict__ bk1,
                            const float* __restrict__ bq2, const float* __restrict__ bk2,
                            const float* __restrict__ bvv,
                            const float* __restrict__ lq1, const float* __restrict__ lk1,
                            const float* __restrict__ lq2, const float* __restrict__ lk2,
                            const float* __restrict__ freq_deltas, const float* __restrict__ freq_bias,
                            bf16* __restrict__ w1T, bf16* __restrict__ w2T, bf16* __restrict__ qkvT,
                            float* __restrict__ bqkv, float* __restrict__ freqs, float* __restrict__ lamb) {
  int tid = blockIdx.x * blockDim.x + threadIdx.x;
  int nthr = gridDim.x * blockDim.x;
  for (int i = tid; i < 512 * 128; i += nthr) {
    int o = i >> 9, k = i & 511;
    w1T[i] = (bf16)w1[k * 128 + o];
  }
  for (int i = tid; i < 64 * 128; i += nthr) {
    int o = i >> 7, k = i & 127;
    w2T[i] = (bf16)w2[k * 64 + o];
  }
  for (int i = tid; i < 320 * 64; i += nthr) {
    int r = i >> 6, k = i & 63;
    const float* W = (r < 64) ? wq1 : (r < 128) ? wk1 : (r < 192) ? wq2 : (r < 256) ? wk2 : wvw;
    qkvT[i] = (bf16)W[k * 64 + (r & 63)];
  }
  for (int i = tid; i < 320; i += nthr) {
    const float* B = (i < 64) ? bq1 : (i < 128) ? bk1 : (i < 192) ? bq2 : (i < 256) ? bk2 : bvv;
    bqkv[i] = B[i & 63];
  }
  if (blockIdx.x == 0) {
    if (threadIdx.x == 0) {
      float acc = freq_bias[0];
      for (int f = 0; f < 16; f++) {
        acc += log1pf(expf(freq_deltas[f])) + 0.25f;
        freqs[f] = 50.0f * tanhf(acc * (1.0f / 50.0f));
      }
    }
    if (threadIdx.x >= 64 && threadIdx.x < 128) {
      int l = threadIdx.x - 64;
      float s1 = wave_sum64(lq1[l] * lk1[l]);
      float s2 = wave_sum64(lq2[l] * lk2[l]);
      if (l == 0) lamb[0] = expf(s1) - expf(s2) + 0.2f;
    }
  }
}

// ---------------------------------------------------------------- new_e
__global__ void newe_kernel(const float* __restrict__ e, const float* __restrict__ rw,
                            const float* __restrict__ rb, const float* __restrict__ aw,
                            const float* __restrict__ freqs, float* __restrict__ newe) {
  int n = blockIdx.x * blockDim.x + threadIdx.x;
  if (n >= NN) return;
  float fr[16];
#pragma unroll
  for (int f = 0; f < 16; f++) fr[f] = freqs[f];
  float ev = e[n], p = 1.0f, acc = 0.0f;
  for (int k = 0; k < 10; k++) {
    p *= ev;
    float s = rb[k] + rw[k * 33];
#pragma unroll
    for (int f = 0; f < 16; f++) {
      float ph = p * fr[f];
      s += 0.25f * (__sinf(ph) * rw[k * 33 + 1 + f] + __cosf(ph) * rw[k * 33 + 17 + f]);
    }
    acc += s * aw[k];
  }
  newe[n] = acc;
}

// ---------------------------------------------------------------- G1
__global__ __launch_bounds__(256) void g1_kernel(const float* __restrict__ x, const bf16* __restrict__ w1T,
                                                 const float* __restrict__ b1, bf16* __restrict__ t1b) {
  __shared__ bf16 la[64][40];
  __shared__ bf16 lb[128][40];
  const int bm = blockIdx.x * 64;
  const int lane = threadIdx.x & 63, wvid = threadIdx.x >> 6;
  const int am = threadIdx.x >> 2, aseg = (threadIdx.x & 3) * 8;
  const int arow = bm + am;
  f32x4 acc[8] = {};
  float4 aLo, aHi;
  uint4 bChunk[2];
  auto fetchAll = [&](int k0) {
    if (arow < NN) {
      const float4* p = (const float4*)(x + (size_t)arow * 512 + k0 + aseg);
      aLo = p[0]; aHi = p[1];
    } else {
      aLo = make_float4(0.f, 0.f, 0.f, 0.f); aHi = aLo;
    }
#pragma unroll
    for (int r = 0; r < 2; r++) {
      int slot = threadIdx.x * 2 + r;
      int n = slot >> 2, seg = (slot & 3) * 8;
      bChunk[r] = *(const uint4*)(w1T + n * 512 + k0 + seg);
    }
  };
  auto store = [&]() {
    union { uint4 v; bf16 b[8]; } pk;
    float av[8] = {aLo.x, aLo.y, aLo.z, aLo.w, aHi.x, aHi.y, aHi.z, aHi.w};
#pragma unroll
    for (int t = 0; t < 8; t++) pk.b[t] = (bf16)av[t];
    *(uint4*)&la[am][aseg] = pk.v;
#pragma unroll
    for (int r = 0; r < 2; r++) {
      int slot = threadIdx.x * 2 + r;
      int n = slot >> 2, seg = (slot & 3) * 8;
      *(uint4*)&lb[n][seg] = bChunk[r];
    }
  };
  fetchAll(0);
  for (int k0 = 0; k0 < 512; k0 += 32) {
    store();
    if (k0 + 32 < 512) fetchAll(k0 + 32);
    __syncthreads();
    bf16x8 af = *(const bf16x8*)&la[wvid * 16 + (lane & 15)][(lane >> 4) * 8];
#pragma unroll
    for (int s = 0; s < 8; s++) {
      bf16x8 bfr = *(const bf16x8*)&lb[s * 16 + (lane & 15)][(lane >> 4) * 8];
      acc[s] = __builtin_amdgcn_mfma_f32_16x16x32_bf16(af, bfr, acc[s], 0, 0, 0);
    }
    __syncthreads();
  }
#pragma unroll
  for (int s = 0; s < 8; s++) {
    int col = s * 16 + (lane & 15);
    float bvv = b1[col];
#pragma unroll
    for (int r = 0; r < 4; r++) {
      int row = bm + wvid * 16 + (lane >> 4) * 4 + r;
      if (row < NN) {
        float v = acc[s][r] + bvv;
        t1b[(size_t)row * 128 + col] = (bf16)(v > 0.f ? v : 0.f);
      }
    }
  }
}

// ---------------------------------------------------------------- G2 (+ fused mha-LN epilogue)
__global__ __launch_bounds__(256) void g2_kernel(const bf16* __restrict__ t1b, const bf16* __restrict__ w2T,
                                                 const float* __restrict__ b2, const float* __restrict__ lng,
                                                 const float* __restrict__ lnb, float* __restrict__ h,
                                                 bf16* __restrict__ hT, bf16* __restrict__ mh) {
  __shared__ bf16 la[64][72];
  __shared__ bf16 lb[64][72];
  const int bm = blockIdx.x * 64;
  const int lane = threadIdx.x & 63, wvid = threadIdx.x >> 6;
  f32x4 acc[4] = {};
  for (int k0 = 0; k0 < 128; k0 += 64) {
#pragma unroll
    for (int r = 0; r < 2; r++) {
      int slot = threadIdx.x * 2 + r;
      int m = slot >> 3, seg = (slot & 7) * 8;
      int row = bm + m;
      uint4 val = make_uint4(0u, 0u, 0u, 0u);
      if (row < NN) val = *(const uint4*)(t1b + (size_t)row * 128 + k0 + seg);
      *(uint4*)&la[m][seg] = val;
      *(uint4*)&lb[m][seg] = *(const uint4*)(w2T + m * 128 + k0 + seg);
    }
    __syncthreads();
#pragma unroll
    for (int ks = 0; ks < 2; ks++) {
      bf16x8 af = *(const bf16x8*)&la[wvid * 16 + (lane & 15)][ks * 32 + (lane >> 4) * 8];
#pragma unroll
      for (int s = 0; s < 4; s++) {
        bf16x8 bfr = *(const bf16x8*)&lb[s * 16 + (lane & 15)][ks * 32 + (lane >> 4) * 8];
        acc[s] = __builtin_amdgcn_mfma_f32_16x16x32_bf16(af, bfr, acc[s], 0, 0, 0);
      }
    }
    __syncthreads();
  }
  float bv4[4], g4[4], lb4[4];
#pragma unroll
  for (int s = 0; s < 4; s++) {
    int col = s * 16 + (lane & 15);
    bv4[s] = b2[col]; g4[s] = lng[col]; lb4[s] = lnb[col];
  }
#pragma unroll
  for (int r = 0; r < 4; r++) {
    float vals[4], psum = 0.f;
#pragma unroll
    for (int s = 0; s < 4; s++) { vals[s] = acc[s][r] + bv4[s]; psum += vals[s]; }
#pragma unroll
    for (int msk = 1; msk < 16; msk <<= 1) psum += __shfl_xor(psum, msk, 64);
    float mean = psum * (1.0f / 64.0f);
    float pvar = 0.f;
#pragma unroll
    for (int s = 0; s < 4; s++) { float dd = vals[s] - mean; pvar += dd * dd; }
#pragma unroll
    for (int msk = 1; msk < 16; msk <<= 1) pvar += __shfl_xor(pvar, msk, 64);
    float rsq = rsqrtf(pvar * (1.0f / 64.0f) + 1e-5f);
    int row = bm + wvid * 16 + (lane >> 4) * 4 + r;
    if (row < NN) {
#pragma unroll
      for (int s = 0; s < 4; s++) {
        int col = s * 16 + (lane & 15);
        float v = vals[s];
        h[(size_t)row * 64 + col] = v;
        hT[(size_t)col * NN + row] = (bf16)v;
        mh[(size_t)row * 64 + col] = (bf16)(g4[s] * (v - mean) * rsq + lb4[s]);
      }
    }
  }
}

// ---------------------------------------------------------------- QKV
__global__ __launch_bounds__(256) void qkv_kernel(const bf16* __restrict__ mh, const bf16* __restrict__ qkvT,
                                                  const float* __restrict__ bqkv,
                                                  bf16* __restrict__ qq, bf16* __restrict__ kv) {
  __shared__ bf16 la[64][72];
  __shared__ bf16 lb[320][72];
  const int bm = blockIdx.x * 64;
  const int lane = threadIdx.x & 63, wvid = threadIdx.x >> 6;
#pragma unroll
  for (int r = 0; r < 2; r++) {
    int slot = threadIdx.x * 2 + r;
    int m = slot >> 3, seg = (slot & 7) * 8;
    int row = bm + m;
    uint4 val = make_uint4(0u, 0u, 0u, 0u);
    if (row < NN) val = *(const uint4*)(mh + (size_t)row * 64 + seg);
    *(uint4*)&la[m][seg] = val;
  }
#pragma unroll
  for (int r = 0; r < 10; r++) {
    int slot = threadIdx.x * 10 + r;
    int n = slot >> 3, seg = (slot & 7) * 8;
    *(uint4*)&lb[n][seg] = *(const uint4*)(qkvT + n * 64 + seg);
  }
  __syncthreads();
  f32x4 acc[20] = {};
#pragma unroll
  for (int ks = 0; ks < 2; ks++) {
    bf16x8 af = *(const bf16x8*)&la[wvid * 16 + (lane & 15)][ks * 32 + (lane >> 4) * 8];
#pragma unroll
    for (int s = 0; s < 20; s++) {
      bf16x8 bfr = *(const bf16x8*)&lb[s * 16 + (lane & 15)][ks * 32 + (lane >> 4) * 8];
      acc[s] = __builtin_amdgcn_mfma_f32_16x16x32_bf16(af, bfr, acc[s], 0, 0, 0);
    }
  }
#pragma unroll
  for (int s = 0; s < 20; s++) {
    int col = s * 16 + (lane & 15);
    float bvv = bqkv[col];
    bf16* dst; int dc, stride;
    if (col < 64)       { dst = qq; dc = col;       stride = 128; }
    else if (col < 128) { dst = kv; dc = col - 64;  stride = 192; }
    else if (col < 192) { dst = qq; dc = col - 64;  stride = 128; }
    else                { dst = kv; dc = col - 128; stride = 192; }
#pragma unroll
    for (int r = 0; r < 4; r++) {
      int row = bm + wvid * 16 + (lane >> 4) * 4 + r;
      if (row < NN) dst[(size_t)row * stride + dc] = (bf16)(acc[s][r] + bvv);
    }
  }
}

// ---------------------------------------------------------------- R1
__global__ __launch_bounds__(256) void r1_kernel(const bf16* __restrict__ kv, float* __restrict__ part) {
  int b = blockIdx.x;
  int c1 = threadIdx.x & 63, grp = threadIdx.x >> 6;
  int r0 = b * 16;
  float a1[16] = {}, a2[16] = {};
  for (int r = 0; r < 16; r++) {
    const bf16* rowp = kv + (size_t)(r0 + r) * 192;
    float k1 = (float)rowp[c1];
    float k2 = (float)rowp[64 + c1];
    union { uint4 v; bf16 b[8]; } v0, v1;
    v0.v = *(const uint4*)(rowp + 128 + grp * 16);
    v1.v = *(const uint4*)(rowp + 136 + grp * 16);
#pragma unroll
    for (int q = 0; q < 8; q++) {
      float va = (float)v0.b[q], vb = (float)v1.b[q];
      a1[q] += k1 * va; a2[q] += k2 * va;
      a1[8 + q] += k1 * vb; a2[8 + q] += k2 * vb;
    }
  }
  float* p1 = part + (size_t)b * 8192 + (size_t)c1 * 64 + grp * 16;
  float* p2 = p1 + 4096;
#pragma unroll
  for (int q = 0; q < 16; q++) { p1[q] = a1[q]; p2[q] = a2[q]; }
}

// ---------------------------------------------------------------- R2a
__global__ __launch_bounds__(256) void r2a_kernel(const float* __restrict__ part, float* __restrict__ part2) {
  int flat = blockIdx.x * 256 + threadIdx.x;
  int y = blockIdx.y;
  int b0 = y * 79, b1 = min(625, b0 + 79);
  float s = 0.f;
  for (int b = b0; b < b1; b++) s += part[(size_t)b * 8192 + flat];
  part2[(size_t)flat * 8 + y] = s;
}

// ---------------------------------------------------------------- R2b
__global__ void r2b_kernel(const float* __restrict__ part2, const float* __restrict__ lamb, bf16* __restrict__ Bt) {
  int flat = blockIdx.x * 256 + threadIdx.x;
  int mat = flat >> 12, rem = flat & 4095;
  int d = rem >> 6, c = rem & 63;
  f32x4 lo = *(const f32x4*)(part2 + (size_t)flat * 8);
  f32x4 hi = *(const f32x4*)(part2 + (size_t)flat * 8 + 4);
  float s = lo[0] + lo[1] + lo[2] + lo[3] + hi[0] + hi[1] + hi[2] + hi[3];
  float v = mat ? (-lamb[0] * s) : s;
  Bt[c * 128 + mat * 64 + d] = (bf16)v;
}

// ---------------------------------------------------------------- D split-K (R2 structure, raw barriers)
// dpart[sk][c][j] = sum_{i in split} hT[c][i] * u[i][j]
__global__ __launch_bounds__(256) void d_split_kernel(const float* __restrict__ u, const bf16* __restrict__ hT,
                                                      float* __restrict__ dpart) {
  __shared__ bf16 la[64][72];   // hT tile [c][i]
  __shared__ bf16 lb[64][72];   // u^T tile [j][i], XOR-swizzled in i
  const int j0 = blockIdx.x * 64;
  const int sk = blockIdx.y;
  const int c0 = sk * CPS, c1e = min(CHUNKS, c0 + CPS);
  const int t = threadIdx.x;
  const int lane = t & 63, wv = t >> 6;
  const int jl = (t & 15) * 4;
  const int ir = (t >> 4) * 4;
  f32x4 acc[4] = {};
  uint4 aC[2];
  float4 bC[4];
  auto fetchAll = [&](int i0) {
#pragma unroll
    for (int r = 0; r < 2; r++) {
      int slot = t * 2 + r;
      int c = slot >> 3, seg = (slot & 7) * 8;
      int i = i0 + seg;
      if (i + 7 < NN) aC[r] = *(const uint4*)(hT + (size_t)c * NN + i);
      else {
        union { uint4 v; bf16 b[8]; } tu;
#pragma unroll
        for (int q = 0; q < 8; q++) tu.b[q] = (i + q < NN) ? hT[(size_t)c * NN + i + q] : (bf16)0.f;
        aC[r] = tu.v;
      }
    }
#pragma unroll
    for (int q = 0; q < 4; q++) {
      int i = i0 + ir + q;
      if (i < NN && (j0 + jl + 3) < NN) bC[q] = *(const float4*)(u + (size_t)i * NN + j0 + jl);
      else if (i < NN) {
        float tmp[4];
#pragma unroll
        for (int q2 = 0; q2 < 4; q2++) tmp[q2] = (j0 + jl + q2 < NN) ? u[(size_t)i * NN + j0 + jl + q2] : 0.f;
        bC[q] = make_float4(tmp[0], tmp[1], tmp[2], tmp[3]);
      } else bC[q] = make_float4(0.f, 0.f, 0.f, 0.f);
    }
  };
  auto storeAll = [&]() {
#pragma unroll
    for (int r = 0; r < 2; r++) {
      int slot = t * 2 + r;
      int c = slot >> 3, seg = (slot & 7) * 8;
      *(uint4*)&la[c][seg] = aC[r];
    }
#pragma unroll
    for (int q2 = 0; q2 < 4; q2++) {
      int j = jl + q2;
      int isw = ir ^ (((j >> 2) & 3) << 3);
      union { uint2 w; bf16 b[4]; } pk;
      pk.b[0] = (bf16)((float*)&bC[0])[q2];
      pk.b[1] = (bf16)((float*)&bC[1])[q2];
      pk.b[2] = (bf16)((float*)&bC[2])[q2];
      pk.b[3] = (bf16)((float*)&bC[3])[q2];
      *(uint2*)&lb[j][isw] = pk.w;
    }
  };
  fetchAll(c0 * 64);
  for (int ch = c0; ch < c1e; ch++) {
    storeAll();                              // waits (counted) only on this chunk's regs
    if (ch + 1 < c1e) fetchAll((ch + 1) * 64); // issue next loads; they fly across barriers
    SYNC_LDS();
#pragma unroll
    for (int ks = 0; ks < 2; ks++) {
      bf16x8 af = *(const bf16x8*)&la[wv * 16 + (lane & 15)][ks * 32 + (lane >> 4) * 8];
#pragma unroll
      for (int s = 0; s < 4; s++) {
        int j = s * 16 + (lane & 15);
        int ioff = (ks * 32 + (lane >> 4) * 8) ^ (((j >> 2) & 3) << 3);
        bf16x8 bfr = *(const bf16x8*)&lb[j][ioff];
        acc[s] = __builtin_amdgcn_mfma_f32_16x16x32_bf16(af, bfr, acc[s], 0, 0, 0);
      }
    }
    SYNC_LDS();
  }
#pragma unroll
  for (int s = 0; s < 4; s++) {
    int j = j0 + s * 16 + (lane & 15);
#pragma unroll
    for (int r = 0; r < 4; r++) {
      int c = wv * 16 + (lane >> 4) * 4 + r;
      dpart[((size_t)sk * 64 + c) * J48 + j] = acc[s][r];
    }
  }
}

// ---------------------------------------------------------------- D reduce
__global__ void dred_kernel(const float* __restrict__ dpart, const float* __restrict__ newe,
                            bf16* __restrict__ wutxT) {
  int idx = blockIdx.x * 256 + threadIdx.x;
  int c = idx / 2512;
  int j = (idx - c * 2512) * 4;
  if (c >= 64 || j >= NN) return;
  f32x4 s = {};
  for (int sk = 0; sk < SPLITS; sk++)
    s += *(const f32x4*)(dpart + ((size_t)sk * 64 + c) * J48 + j);
  union { uint2 w; bf16 b[4]; } pk;
#pragma unroll
  for (int q = 0; q < 4; q++) pk.b[q] = (bf16)(newe[j + q] * s[q]);
  *(uint2*)&wutxT[(size_t)c * NN + j] = pk.w;
}

// ---------------------------------------------------------------- E split-K (R2 structure, raw barriers)
// epart[sk][i][c] = sum_{j in split} u[i][j] * wutxT[c][j]
__global__ __launch_bounds__(256) void e_split_kernel(const float* __restrict__ u, const bf16* __restrict__ wutxT,
                                                      float* __restrict__ epart) {
  __shared__ bf16 la[64][72];   // u rows bf16 [i_local][j]
  __shared__ bf16 lb[64][72];   // wutxT [c][j]
  const int bm = blockIdx.x * 64;
  const int sk = blockIdx.y;
  const int c0 = sk * CPS, c1e = min(CHUNKS, c0 + CPS);
  const int t = threadIdx.x;
  const int lane = t & 63, wv = t >> 6;
  const int mA = t >> 2, segA = (t & 3) * 16;
  const int mrow = bm + mA;
  f32x4 acc[4] = {};
  float4 aC[4];
  uint4 bC[2];
  auto fetchAll = [&](int j0) {
    int j = j0 + segA;
    if (mrow < NN && j + 15 < NN) {
      const float4* p = (const float4*)(u + (size_t)mrow * NN + j);
      aC[0] = p[0]; aC[1] = p[1]; aC[2] = p[2]; aC[3] = p[3];
    } else {
#pragma unroll
      for (int q = 0; q < 4; q++) {
        float tmp[4];
#pragma unroll
        for (int q2 = 0; q2 < 4; q2++) {
          int jj = j + q * 4 + q2;
          tmp[q2] = (mrow < NN && jj < NN) ? u[(size_t)mrow * NN + jj] : 0.f;
        }
        aC[q] = make_float4(tmp[0], tmp[1], tmp[2], tmp[3]);
      }
    }
#pragma unroll
    for (int r = 0; r < 2; r++) {
      int slot = t * 2 + r;
      int c = slot >> 3, seg = (slot & 7) * 8;
      int jj = j0 + seg;
      if (jj + 7 < NN) bC[r] = *(const uint4*)(wutxT + (size_t)c * NN + jj);
      else {
        union { uint4 v; bf16 b[8]; } tu;
#pragma unroll
        for (int q = 0; q < 8; q++) tu.b[q] = (jj + q < NN) ? wutxT[(size_t)c * NN + jj + q] : (bf16)0.f;
        bC[r] = tu.v;
      }
    }
  };
  auto storeAll = [&]() {
    union { uint4 v[2]; bf16 b[16]; } pk;
#pragma unroll
    for (int q = 0; q < 4; q++)
#pragma unroll
      for (int q2 = 0; q2 < 4; q2++) pk.b[q * 4 + q2] = (bf16)((float*)&aC[q])[q2];
    *(uint4*)&la[mA][segA] = pk.v[0];
    *(uint4*)&la[mA][segA + 8] = pk.v[1];
#pragma unroll
    for (int r = 0; r < 2; r++) {
      int slot = t * 2 + r;
      int c = slot >> 3, seg = (slot & 7) * 8;
      *(uint4*)&lb[c][seg] = bC[r];
    }
  };
  fetchAll(c0 * 64);
  for (int ch = c0; ch < c1e; ch++) {
    storeAll();
    if (ch + 1 < c1e) fetchAll((ch + 1) * 64);
    SYNC_LDS();
#pragma unroll
    for (int ks = 0; ks < 2; ks++) {
      bf16x8 af = *(const bf16x8*)&la[wv * 16 + (lane & 15)][ks * 32 + (lane >> 4) * 8];
#pragma unroll
      for (int s = 0; s < 4; s++) {
        bf16x8 bfr = *(const bf16x8*)&lb[s * 16 + (lane & 15)][ks * 32 + (lane >> 4) * 8];
        acc[s] = __builtin_amdgcn_mfma_f32_16x16x32_bf16(af, bfr, acc[s], 0, 0, 0);
      }
    }
    SYNC_LDS();
  }
#pragma unroll
  for (int s = 0; s < 4; s++) {
    int col = s * 16 + (lane & 15);
#pragma unroll
    for (int r = 0; r < 4; r++) {
      int row = wv * 16 + (lane >> 4) * 4 + r;
      epart[((size_t)sk * J48 + bm + row) * 64 + col] = acc[s][r];
    }
  }
}

// ---------------------------------------------------------------- E reduce
__global__ void ered_kernel(const float* __restrict__ epart, float* __restrict__ h_fur) {
  int idx = blockIdx.x * 256 + threadIdx.x;
  if (idx >= NN * 16) return;
  size_t off = (size_t)idx * 4;
  f32x4 s = {};
  for (int sk = 0; sk < SPLITS; sk++)
    s += *(const f32x4*)(epart + (size_t)sk * (J48 * 64) + off);
  *(f32x4*)(h_fur + off) = s;
}

// ---------------------------------------------------------------- H: xa = qq@Bt ; LN ; *0.8
__global__ __launch_bounds__(256) void hattn_kernel(const bf16* __restrict__ qq, const bf16* __restrict__ Bt,
                                                    const float* __restrict__ g, const float* __restrict__ b,
                                                    bf16* __restrict__ xan) {
  __shared__ bf16 la[64][136];
  __shared__ bf16 lb[64][136];
  const int bm = blockIdx.x * 64;
  const int lane = threadIdx.x & 63, wvid = threadIdx.x >> 6;
#pragma unroll
  for (int r = 0; r < 4; r++) {
    int slot = threadIdx.x * 4 + r;
    int m = slot >> 4, seg = (slot & 15) * 8;
    int row = bm + m;
    uint4 val = make_uint4(0u, 0u, 0u, 0u);
    if (row < NN) val = *(const uint4*)(qq + (size_t)row * 128 + seg);
    *(uint4*)&la[m][seg] = val;
    *(uint4*)&lb[m][seg] = *(const uint4*)(Bt + m * 128 + seg);
  }
  __syncthreads();
  f32x4 acc[4] = {};
#pragma unroll
  for (int ks = 0; ks < 4; ks++) {
    bf16x8 af = *(const bf16x8*)&la[wvid * 16 + (lane & 15)][ks * 32 + (lane >> 4) * 8];
#pragma unroll
    for (int s = 0; s < 4; s++) {
      bf16x8 bfr = *(const bf16x8*)&lb[s * 16 + (lane & 15)][ks * 32 + (lane >> 4) * 8];
      acc[s] = __builtin_amdgcn_mfma_f32_16x16x32_bf16(af, bfr, acc[s], 0, 0, 0);
    }
  }
#pragma unroll
  for (int r = 0; r < 4; r++) {
    float psum = acc[0][r] + acc[1][r] + acc[2][r] + acc[3][r];
#pragma unroll
    for (int msk = 1; msk < 16; msk <<= 1) psum += __shfl_xor(psum, msk, 64);
    float mean = psum * (1.0f / 64.0f);
    float pvar = 0.f;
#pragma unroll
    for (int s = 0; s < 4; s++) { float dd = acc[s][r] - mean; pvar += dd * dd; }
#pragma unroll
    for (int msk = 1; msk < 16; msk <<= 1) pvar += __shfl_xor(pvar, msk, 64);
    float rsq = rsqrtf(pvar * (1.0f / 64.0f) + 1e-5f);
    int row = bm + wvid * 16 + (lane >> 4) * 4 + r;
    if (row < NN) {
#pragma unroll
      for (int s = 0; s < 4; s++) {
        int col = s * 16 + (lane & 15);
        float o = 0.8f * (g[col] * (acc[s][r] - mean) * rsq + b[col]);
        xan[(size_t)row * 64 + col] = (bf16)o;
      }
    }
  }
}

// ---------------------------------------------------------------- final
__global__ __launch_bounds__(256) void final_kernel(const float* __restrict__ h, const float* __restrict__ h_fur,
                                                    const bf16* __restrict__ xan,
                                                    const float* __restrict__ out_w, const float* __restrict__ out_b,
                                                    const float* __restrict__ gg, const float* __restrict__ gb,
                                                    const float* __restrict__ gw, const float* __restrict__ gbias,
                                                    const float* __restrict__ fg, const float* __restrict__ fb,
                                                    const float* __restrict__ fw1, const float* __restrict__ fb1,
                                                    const float* __restrict__ fw2, const float* __restrict__ fb2,
                                                    float* __restrict__ out) {
  __shared__ float s_ow[64][64];
  __shared__ float s_w1[64][64];
  __shared__ float s_w2[64][64];
  __shared__ float s_gw[192][3];
  __shared__ float s_row[4][64];
  const int lane = threadIdx.x & 63, wvid = threadIdx.x >> 6;
  for (int i = threadIdx.x; i < 4096; i += 256) {
    ((float*)s_ow)[i] = out_w[i];
    ((float*)s_w1)[i] = fw1[i];
    ((float*)s_w2)[i] = fw2[i];
  }
  for (int i = threadIdx.x; i < 576; i += 256) ((float*)s_gw)[i] = gw[i];
  const int row = blockIdx.x * 4 + wvid;
  float x_h = h[(size_t)row * 64 + lane];
  float x_f = h_fur[(size_t)row * 64 + lane];
  float x_a = (float)xan[(size_t)row * 64 + lane];
  s_row[wvid][lane] = x_a;
  __syncthreads();
  float mha = out_b[lane];
#pragma unroll 8
  for (int d = 0; d < 64; d++) mha += s_row[wvid][d] * s_ow[d][lane];
  float m3 = wave_sum64(x_h + mha + x_f) * (1.0f / 192.0f);
  float dh = x_h - m3, dm = mha - m3, df = x_f - m3;
  float v3 = wave_sum64(dh * dh + dm * dm + df * df) * (1.0f / 192.0f);
  float rs3 = rsqrtf(v3 + 1e-5f);
  float l0 = gg[lane] * dh * rs3 + gb[lane];
  float l1 = gg[64 + lane] * dm * rs3 + gb[64 + lane];
  float l2 = gg[128 + lane] * df * rs3 + gb[128 + lane];
  float p0 = l0 * s_gw[lane][0] + l1 * s_gw[64 + lane][0] + l2 * s_gw[128 + lane][0];
  float p1 = l0 * s_gw[lane][1] + l1 * s_gw[64 + lane][1] + l2 * s_gw[128 + lane][1];
  float p2 = l0 * s_gw[lane][2] + l1 * s_gw[64 + lane][2] + l2 * s_gw[128 + lane][2];
  p0 = wave_sum64(p0) + gbias[0];
  p1 = wave_sum64(p1) + gbias[1];
  p2 = wave_sum64(p2) + gbias[2];
  float mx = fmaxf(p0, fmaxf(p1, p2));
  float e0 = expf(p0 - mx), e1 = expf(p1 - mx), e2 = expf(p2 - mx);
  float inv = 1.0f / (e0 + e1 + e2);
  float mix = x_h * (e0 * inv) + mha * (e1 * inv) + x_f * (e2 * inv);
  float mf = wave_sum64(mix) * (1.0f / 64.0f);
  float dmx = mix - mf;
  float vf = wave_sum64(dmx * dmx) * (1.0f / 64.0f);
  float f = fg[lane] * dmx * rsqrtf(vf + 1e-5f) + fb[lane];
  __syncthreads();
  s_row[wvid][lane] = f;
  __syncthreads();
  float t1 = fb1[lane];
#pragma unroll 8
  for (int d = 0; d < 64; d++) t1 += s_row[wvid][d] * s_w1[d][lane];
  t1 = 0.5f * t1 * (1.0f + erff(t1 * 0.70710678118654752f));
  __syncthreads();
  s_row[wvid][lane] = t1;
  __syncthreads();
  float f2 = fb2[lane];
#pragma unroll 8
  for (int d = 0; d < 64; d++) f2 += s_row[wvid][d] * s_w2[d][lane];
  out[(size_t)row * 64 + lane] = mix + f2;
}

// ================================================================ launch
extern "C" void kernel_launch(void* const* d_in, const int* in_sizes, int n_in,
                              void* d_out, int out_size, void* d_ws, size_t ws_size,
                              hipStream_t stream) {
  const float* e          = (const float*)d_in[0];
  const float* u          = (const float*)d_in[1];
  const float* x          = (const float*)d_in[2];
  const float* fe_w1      = (const float*)d_in[3];
  const float* fe_b1      = (const float*)d_in[4];
  const float* fe_w2      = (const float*)d_in[5];
  const float* fe_b2      = (const float*)d_in[6];
  const float* freq_deltas= (const float*)d_in[7];
  const float* freq_bias  = (const float*)d_in[8];
  const float* readout_w  = (const float*)d_in[9];
  const float* readout_b  = (const float*)d_in[10];
  const float* alpha_w    = (const float*)d_in[11];
  const float* mha_ln_g   = (const float*)d_in[12];
  const float* mha_ln_b   = (const float*)d_in[13];
  const float* wq1        = (const float*)d_in[14];
  const float* bq1        = (const float*)d_in[15];
  const float* wk1        = (const float*)d_in[16];
  const float* bk1        = (const float*)d_in[17];
  const float* wq2        = (const float*)d_in[18];
  const float* bq2        = (const float*)d_in[19];
  const float* wk2        = (const float*)d_in[20];
  const float* bk2        = (const float*)d_in[21];
  const float* wv_in      = (const float*)d_in[22];
  const float* bv_in      = (const float*)d_in[23];
  const float* lq1        = (const float*)d_in[24];
  const float* lk1        = (const float*)d_in[25];
  const float* lq2        = (const float*)d_in[26];
  const float* lk2        = (const float*)d_in[27];
  const float* attn_ln_g  = (const float*)d_in[28];
  const float* attn_ln_b  = (const float*)d_in[29];
  const float* out_w      = (const float*)d_in[30];
  const float* out_b      = (const float*)d_in[31];
  const float* gate_ln_g  = (const float*)d_in[32];
  const float* gate_ln_b  = (const float*)d_in[33];
  const float* gate_w     = (const float*)d_in[34];
  const float* gate_b     = (const float*)d_in[35];
  const float* ffn_ln_g   = (const float*)d_in[36];
  const float* ffn_ln_b   = (const float*)d_in[37];
  const float* ffn_w1     = (const float*)d_in[38];
  const float* ffn_b1     = (const float*)d_in[39];
  const float* ffn_w2     = (const float*)d_in[40];
  const float* ffn_b2     = (const float*)d_in[41];

  constexpr size_t OFF_H     = 0;               // f32 N*64
  constexpr size_t OFF_T1B   = 2560000;         // bf16 N*128
  constexpr size_t OFF_HT    = 5120000;         // bf16 64*N
  constexpr size_t OFF_MH    = 6400000;         // bf16 N*64
  constexpr size_t OFF_QQ    = 7680000;         // bf16 N*128
  constexpr size_t OFF_KV    = 10240000;        // bf16 N*192
  constexpr size_t OFF_WUTXT = 14080000;        // bf16 64*N
  constexpr size_t OFF_HFUR  = 15360000;        // f32 N*64
  constexpr size_t OFF_XAN   = 17920000;        // bf16 N*64
  constexpr size_t OFF_NEWE  = 19200000;        // f32 N (pad)
  constexpr size_t OFF_BT    = 19240064;        // bf16 64*128
  constexpr size_t OFF_W1T   = 19256448;        // bf16 128*512
  constexpr size_t OFF_W2T   = 19387520;        // bf16 64*128
  constexpr size_t OFF_QKVT  = 19403904;        // bf16 320*64
  constexpr size_t OFF_BQKV  = 19444864;        // f32 320
  constexpr size_t OFF_FREQS = 19446144;        // f32 16
  constexpr size_t OFF_LAM   = 19446208;        // f32 1
  constexpr size_t OFF_BIG   = 19446272;        // part(20.48MB) / dpart / epart alias
  constexpr size_t SZ_SPART  = (size_t)SPLITS * 64 * J48 * 4;   // 20,578,304
  constexpr size_t OFF_PART2 = OFF_BIG + SZ_SPART;              // 256 KB
  constexpr size_t WS_NEED   = OFF_PART2 + 262144;
  if (ws_size < WS_NEED) return;

  char* ws = (char*)d_ws;
  float* h_buf   = (float*)(ws + OFF_H);
  bf16*  t1b     = (bf16*)(ws + OFF_T1B);
  bf16*  hT      = (bf16*)(ws + OFF_HT);
  bf16*  mh      = (bf16*)(ws + OFF_MH);
  bf16*  qq      = (bf16*)(ws + OFF_QQ);
  bf16*  kv      = (bf16*)(ws + OFF_KV);
  bf16*  wutxT   = (bf16*)(ws + OFF_WUTXT);
  float* h_fur   = (float*)(ws + OFF_HFUR);
  bf16*  xan     = (bf16*)(ws + OFF_XAN);
  float* newe    = (float*)(ws + OFF_NEWE);
  bf16*  Bt      = (bf16*)(ws + OFF_BT);
  bf16*  w1T     = (bf16*)(ws + OFF_W1T);
  bf16*  w2T     = (bf16*)(ws + OFF_W2T);
  bf16*  qkvT    = (bf16*)(ws + OFF_QKVT);
  float* bqkv    = (float*)(ws + OFF_BQKV);
  float* freqs   = (float*)(ws + OFF_FREQS);
  float* lamb    = (float*)(ws + OFF_LAM);
  float* part    = (float*)(ws + OFF_BIG);
  float* part2   = (float*)(ws + OFF_PART2);
  float* dpart   = (float*)(ws + OFF_BIG);
  float* epart   = (float*)(ws + OFF_BIG);

  prep_kernel<<<64, 256, 0, stream>>>(fe_w1, fe_w2, wq1, wk1, wq2, wk2, wv_in,
                                      bq1, bk1, bq2, bk2, bv_in,
                                      lq1, lk1, lq2, lk2, freq_deltas, freq_bias,
                                      w1T, w2T, qkvT, bqkv, freqs, lamb);
  newe_kernel<<<40, 256, 0, stream>>>(e, readout_w, readout_b, alpha_w, freqs, newe);
  g1_kernel<<<157, 256, 0, stream>>>(x, w1T, fe_b1, t1b);
  g2_kernel<<<157, 256, 0, stream>>>(t1b, w2T, fe_b2, mha_ln_g, mha_ln_b, h_buf, hT, mh);
  qkv_kernel<<<157, 256, 0, stream>>>(mh, qkvT, bqkv, qq, kv);
  r1_kernel<<<625, 256, 0, stream>>>(kv, part);
  r2a_kernel<<<dim3(32, 8), 256, 0, stream>>>(part, part2);
  r2b_kernel<<<32, 256, 0, stream>>>(part2, lamb, Bt);
  d_split_kernel<<<dim3(157, SPLITS), 256, 0, stream>>>(u, hT, dpart);
  dred_kernel<<<628, 256, 0, stream>>>(dpart, newe, wutxT);
  e_split_kernel<<<dim3(157, SPLITS), 256, 0, stream>>>(u, wutxT, epart);
  ered_kernel<<<625, 256, 0, stream>>>(epart, h_fur);
  hattn_kernel<<<157, 256, 0, stream>>>(qq, Bt, attn_ln_g, attn_ln_b, xan);
  final_kernel<<<2500, 256, 0, stream>>>(h_buf, h_fur, xan, out_w, out_b,
                                         gate_ln_g, gate_ln_b, gate_w, gate_b,
                                         ffn_ln_g, ffn_ln_b, ffn_w1, ffn_b1, ffn_w2, ffn_b2,
                                         (float*)d_out);
}